// Round 7
// baseline (550.677 us; speedup 1.0000x reference)
//
#include <hip/hip_runtime.h>
#include <hip/hip_bf16.h>

// Sizes (fixed by the problem)
// B=8, N=1024, hidden=256, heads H=4, d_head D=64, entity_dim=31, merged=35

// ---------------------------------------------------------------------------
// k_proj: merged one-hot projection + mask + my-idx
__global__ __launch_bounds__(256) void k_proj(
    const float* __restrict__ agents, const int* __restrict__ my_id,
    const float* __restrict__ Wp, const float* __restrict__ bp,
    float* __restrict__ proj, float* __restrict__ mask, int* __restrict__ idx)
{
  int blk = blockIdx.x;
  int b = blk >> 10, n = blk & 1023;
  __shared__ float arow[32];
  int t = threadIdx.x;
  if (t < 31) arow[t] = agents[((size_t)(b * 1024 + n)) * 31 + t];
  __syncthreads();
  float id = arow[0];
  int npc = (int)arow[1];
  float acc = bp[t] + id * Wp[t] + Wp[(1 + npc) * 256 + t];
#pragma unroll
  for (int c = 2; c < 31; ++c) acc += arow[c] * Wp[(4 + c) * 256 + t];
  proj[((size_t)(b * 1024 + n)) * 256 + t] = acc;
  if (t == 0) {
    mask[b * 1024 + n] = (id != 0.f) ? 1.f : 0.f;
    if (id == (float)my_id[b]) atomicMin(&idx[b], n);
  }
}

// ---------------------------------------------------------------------------
// Generic fp32 GEMM: C[M x 256] = A[M x K] * B[K x 256] (+bias), M = 8192
__global__ __launch_bounds__(256) void k_gemm(
    const float* __restrict__ A, const float* __restrict__ B,
    const float* __restrict__ bias, float* __restrict__ C, int K)
{
  __shared__ float As[64][68];  // [k][i]
  __shared__ float Bs[64][68];  // [k][j]
  int tid = threadIdx.x;
  int bi = blockIdx.x >> 2;   // 0..127
  int bj = blockIdx.x & 3;    // 0..3
  int i0 = bi << 6, j0 = bj << 6;
  int ti4 = (tid & 15) << 2;
  int tj4 = (tid >> 4) << 2;
  int r = tid >> 2;
  int c0 = (tid & 3) << 4;
  float acc[4][4];
#pragma unroll
  for (int a = 0; a < 4; ++a)
#pragma unroll
    for (int q = 0; q < 4; ++q) acc[a][q] = 0.f;

  for (int k0 = 0; k0 < K; k0 += 64) {
    const float4* Ap4 = (const float4*)(A + (size_t)(i0 + r) * K + k0 + c0);
    float4 aa0 = Ap4[0], aa1 = Ap4[1], aa2 = Ap4[2], aa3 = Ap4[3];
    As[c0 + 0][r] = aa0.x; As[c0 + 1][r] = aa0.y; As[c0 + 2][r] = aa0.z; As[c0 + 3][r] = aa0.w;
    As[c0 + 4][r] = aa1.x; As[c0 + 5][r] = aa1.y; As[c0 + 6][r] = aa1.z; As[c0 + 7][r] = aa1.w;
    As[c0 + 8][r] = aa2.x; As[c0 + 9][r] = aa2.y; As[c0 +10][r] = aa2.z; As[c0 +11][r] = aa2.w;
    As[c0 +12][r] = aa3.x; As[c0 +13][r] = aa3.y; As[c0 +14][r] = aa3.z; As[c0 +15][r] = aa3.w;
    const float4* Bp4 = (const float4*)(B + (size_t)(k0 + r) * 256 + j0 + c0);
    float4 bb0 = Bp4[0], bb1 = Bp4[1], bb2 = Bp4[2], bb3 = Bp4[3];
    *(float4*)&Bs[r][c0 + 0]  = bb0;
    *(float4*)&Bs[r][c0 + 4]  = bb1;
    *(float4*)&Bs[r][c0 + 8]  = bb2;
    *(float4*)&Bs[r][c0 + 12] = bb3;
    __syncthreads();
#pragma unroll
    for (int k = 0; k < 64; ++k) {
      float4 av = *(const float4*)&As[k][ti4];
      float4 bv = *(const float4*)&Bs[k][tj4];
      acc[0][0] += av.x * bv.x; acc[0][1] += av.x * bv.y; acc[0][2] += av.x * bv.z; acc[0][3] += av.x * bv.w;
      acc[1][0] += av.y * bv.x; acc[1][1] += av.y * bv.y; acc[1][2] += av.y * bv.z; acc[1][3] += av.y * bv.w;
      acc[2][0] += av.z * bv.x; acc[2][1] += av.z * bv.y; acc[2][2] += av.z * bv.z; acc[2][3] += av.z * bv.w;
      acc[3][0] += av.w * bv.x; acc[3][1] += av.w * bv.y; acc[3][2] += av.w * bv.z; acc[3][3] += av.w * bv.w;
    }
    __syncthreads();
  }
  float4 bb;
  if (bias) bb = *(const float4*)&bias[j0 + tj4];
  else { bb.x = bb.y = bb.z = bb.w = 0.f; }
#pragma unroll
  for (int ii = 0; ii < 4; ++ii) {
    float4 o;
    o.x = acc[ii][0] + bb.x; o.y = acc[ii][1] + bb.y;
    o.z = acc[ii][2] + bb.z; o.w = acc[ii][3] + bb.w;
    *(float4*)&C[(size_t)(i0 + ti4 + ii) * 256 + j0 + tj4] = o;
  }
}

// ---------------------------------------------------------------------------
// k_edges: e_src/e_dst [B][H][N]
__global__ __launch_bounds__(256) void k_edges(
    const float* __restrict__ h, const float* __restrict__ a_src,
    const float* __restrict__ a_dst, float* __restrict__ esrc, float* __restrict__ edst)
{
  __shared__ float as_[256], ad_[256];
  int t = threadIdx.x;
  as_[t] = a_src[t];
  ad_[t] = a_dst[t];
  __syncthreads();
  int w = t >> 6, l = t & 63;
  int row = blockIdx.x * 4 + w;
  const float* x = h + (size_t)row * 256;
  float ps[4], pd[4];
#pragma unroll
  for (int hh = 0; hh < 4; ++hh) {
    float v = x[hh * 64 + l];
    ps[hh] = v * as_[hh * 64 + l];
    pd[hh] = v * ad_[hh * 64 + l];
  }
#pragma unroll
  for (int hh = 0; hh < 4; ++hh) {
    for (int o = 32; o; o >>= 1) {
      ps[hh] += __shfl_down(ps[hh], o);
      pd[hh] += __shfl_down(pd[hh], o);
    }
  }
  if (l == 0) {
    int b = row >> 10, n = row & 1023;
#pragma unroll
    for (int hh = 0; hh < 4; ++hh) {
      esrc[((b * 4 + hh) << 10) + n] = ps[hh];
      edst[((b * 4 + hh) << 10) + n] = pd[hh];
    }
  }
}

// ---------------------------------------------------------------------------
__global__ __launch_bounds__(256) void k_emax(
    const float* __restrict__ edst, const float* __restrict__ mask, float* __restrict__ Mmax)
{
  int bh = blockIdx.x;
  int b = bh >> 2;
  int t = threadIdx.x;
  float v = -1e30f;
  for (int j = t; j < 1024; j += 256)
    if (mask[(b << 10) + j] != 0.f) v = fmaxf(v, edst[(bh << 10) + j]);
  for (int o = 32; o; o >>= 1) v = fmaxf(v, __shfl_down(v, o));
  __shared__ float red[4];
  if ((t & 63) == 0) red[t >> 6] = v;
  __syncthreads();
  if (t == 0) Mmax[bh] = fmaxf(fmaxf(red[0], red[1]), fmaxf(red[2], red[3]));
}

// ---------------------------------------------------------------------------
// k_attn_part: pass A — unnormalized partial aggregation over a j-slice.
// ITILE=8, JS=2 j-slices -> grid = 8 * 128 * 2 = 2048 blocks = 8 blocks/CU.
// XCD-pinned: b = blockIdx.x & 7. Partials are exact (m is global), so the
// two-slice combine in pass B changes no numerics.
template <int JS>
__global__ __launch_bounds__(256, 8) void k_attn_part(
    const float* __restrict__ h, const float* __restrict__ esrc,
    const float* __restrict__ edst, const float* __restrict__ Mmax,
    const float* __restrict__ mask,
    float* __restrict__ pacc, float* __restrict__ psp)
{
  __shared__ float wT[4][64][12];  // [h][j][i], row = 48B
  __shared__ float esrcL[8][4], mL[8][4];
  __shared__ float maskL[8], MhL[4];

  int t = threadIdx.x;
  int hID = t >> 6, l = t & 63;
  int jq = l >> 4;           // j quarter 0..3
  int dq = (l & 15) << 2;    // d offset 0,4,...,60
  int b = blockIdx.x & 7;    // one b per XCD
  int rem = blockIdx.x >> 3;
  int it = rem & 127;        // i-tile 0..127
  int js = rem >> 7;         // j-slice 0..JS-1
  int i0 = it << 3;
  const int NC = (1024 / JS) >> 6;  // 64-wide chunks per slice
  int jbase = js * (1024 / JS);

  if (t < 8) maskL[t] = mask[(b << 10) + i0 + t];
  if (t < 4) MhL[t] = Mmax[(b << 2) + t];
  if (t < 32) {
    int ii = t >> 2, hh = t & 3;
    esrcL[ii][hh] = esrc[(((b << 2) + hh) << 10) + i0 + ii];
  }
  __syncthreads();
  if (t < 32) {
    int ii = t >> 2, hh = t & 3;
    float m = 0.f;
    if (maskL[ii] != 0.f) {
      float v = esrcL[ii][hh] + MhL[hh];
      m = v > 0.f ? v : 0.2f * v;
    }
    mL[ii][hh] = m;
  }
  __syncthreads();

  float esr[8], mr[8], mskr[8];
#pragma unroll
  for (int i = 0; i < 8; ++i) {
    esr[i] = esrcL[i][hID];
    mr[i] = mL[i][hID];
    mskr[i] = maskL[i];
  }

  float acc[8][4];
  float sp[8];
#pragma unroll
  for (int i = 0; i < 8; ++i) {
    sp[i] = 0.f;
#pragma unroll
    for (int q = 0; q < 4; ++q) acc[i][q] = 0.f;
  }

  const float* ej_base = edst + (((b << 2) + hID) << 10) + jbase;
  const float* mk_base = mask + (b << 10) + jbase;
  const float* h_base = h + ((size_t)((b << 10) + jbase)) * 256 + (hID << 6) + dq;

  for (int c = 0; c < NC; ++c) {
    int j0 = c << 6;
    // ---- weight phase: lane l computes w for j = jbase + j0 + l, 8 rows ----
    float ejv = ej_base[j0 + l];
    float mj = mk_base[j0 + l];
    float w8[8];
#pragma unroll
    for (int i = 0; i < 8; ++i) {
      float w;
      if (mskr[i] != 0.f) {
        float v = esr[i] + ejv;
        v = v > 0.f ? v : 0.2f * v;
        w = (mj != 0.f) ? __expf(v - mr[i]) : 0.f;
      } else {
        w = 1.f;  // invalid row -> uniform over ALL j (matches reference)
      }
      w8[i] = w;
      sp[i] += w;
    }
    *(float4*)&wT[hID][l][0] = *(const float4*)&w8[0];
    *(float4*)&wT[hID][l][4] = *(const float4*)&w8[4];
    __syncthreads();
    // ---- aggregation: thread covers j = j0 + jq + 4s, d = dq..dq+3 ----
    const float* hp = h_base + (size_t)(j0 + jq) * 256;
#pragma unroll 4
    for (int s = 0; s < 16; ++s) {
      float4 hv = *(const float4*)(hp + (size_t)s * 1024);
      int jr = (s << 2) + jq;
      float4 w0 = *(const float4*)&wT[hID][jr][0];
      float4 w1 = *(const float4*)&wT[hID][jr][4];
      acc[0][0] += w0.x * hv.x; acc[0][1] += w0.x * hv.y; acc[0][2] += w0.x * hv.z; acc[0][3] += w0.x * hv.w;
      acc[1][0] += w0.y * hv.x; acc[1][1] += w0.y * hv.y; acc[1][2] += w0.y * hv.z; acc[1][3] += w0.y * hv.w;
      acc[2][0] += w0.z * hv.x; acc[2][1] += w0.z * hv.y; acc[2][2] += w0.z * hv.z; acc[2][3] += w0.z * hv.w;
      acc[3][0] += w0.w * hv.x; acc[3][1] += w0.w * hv.y; acc[3][2] += w0.w * hv.z; acc[3][3] += w0.w * hv.w;
      acc[4][0] += w1.x * hv.x; acc[4][1] += w1.x * hv.y; acc[4][2] += w1.x * hv.z; acc[4][3] += w1.x * hv.w;
      acc[5][0] += w1.y * hv.x; acc[5][1] += w1.y * hv.y; acc[5][2] += w1.y * hv.z; acc[5][3] += w1.y * hv.w;
      acc[6][0] += w1.z * hv.x; acc[6][1] += w1.z * hv.y; acc[6][2] += w1.z * hv.z; acc[6][3] += w1.z * hv.w;
      acc[7][0] += w1.w * hv.x; acc[7][1] += w1.w * hv.y; acc[7][2] += w1.w * hv.z; acc[7][3] += w1.w * hv.w;
    }
    __syncthreads();
  }

  // cross-quarter reduce: lanes l, l^16, l^32, l^48 share (head, d)
#pragma unroll
  for (int i = 0; i < 8; ++i)
#pragma unroll
    for (int q = 0; q < 4; ++q) {
      acc[i][q] += __shfl_xor(acc[i][q], 16);
      acc[i][q] += __shfl_xor(acc[i][q], 32);
    }

  // partial denominators
  size_t pbase = (((size_t)js * 8 + b) * 128 + it) * 8;
#pragma unroll
  for (int i = 0; i < 8; ++i) {
    float v = sp[i];
    for (int o = 32; o; o >>= 1) v += __shfl_xor(v, o);
    if (l == 0) psp[(pbase + i) * 4 + hID] = v;
  }

  // write unnormalized partial aggregation (one writer per column)
  if (jq == 0) {
#pragma unroll
    for (int i = 0; i < 8; ++i) {
      float4 o;
      o.x = acc[i][0]; o.y = acc[i][1]; o.z = acc[i][2]; o.w = acc[i][3];
      *(float4*)&pacc[(pbase + i) * 256 + (hID << 6) + dq] = o;
    }
  }
}

// ---------------------------------------------------------------------------
// k_attn_epi: pass B — combine JS partials, normalize, resid/LN/relu.
// grid = 1024 blocks (b = blk & 7 keeps pacc reads XCD-local).
template <int LAYER, int JS>
__global__ __launch_bounds__(256) void k_attn_epi(
    const float* __restrict__ pacc, const float* __restrict__ psp,
    const float* __restrict__ resid, const float* __restrict__ g,
    const float* __restrict__ be, float* __restrict__ out)
{
  __shared__ float y[8][256];
  __shared__ float sInv[8][4];
  __shared__ float statM[8], statR[8];

  int t = threadIdx.x;
  int hID = t >> 6, l = t & 63;
  int b = blockIdx.x & 7;
  int it = blockIdx.x >> 3;
  int i0 = it << 3;

  if (t < 32) {
    int ii = t >> 2, hh = t & 3;
    float s = 0.f;
#pragma unroll
    for (int js = 0; js < JS; ++js)
      s += psp[((((size_t)js * 8 + b) * 128 + it) * 8 + ii) * 4 + hh];
    sInv[ii][hh] = 1.f / s;
  }
  __syncthreads();

#pragma unroll
  for (int i = 0; i < 8; ++i) {
    float a = 0.f;
#pragma unroll
    for (int js = 0; js < JS; ++js)
      a += pacc[((((size_t)js * 8 + b) * 128 + it) * 8 + i) * 256 + t];
    y[i][t] = a * sInv[i][hID];
  }
  __syncthreads();

  if (LAYER == 1) {
#pragma unroll
    for (int i = 0; i < 8; ++i)
      y[i][t] += resid[((size_t)(b * 1024 + i0 + i)) * 256 + t];
    __syncthreads();
#pragma unroll
    for (int rr = 0; rr < 2; ++rr) {
      int i = (rr << 2) + hID;
      float v0 = y[i][l], v1 = y[i][64 + l], v2 = y[i][128 + l], v3 = y[i][192 + l];
      float s = v0 + v1 + v2 + v3;
      float q = v0 * v0 + v1 * v1 + v2 * v2 + v3 * v3;
      for (int o = 32; o; o >>= 1) { s += __shfl_xor(s, o); q += __shfl_xor(q, o); }
      if (l == 0) {
        float mean = s * (1.f / 256.f);
        float var = q * (1.f / 256.f) - mean * mean;
        statM[i] = mean;
        statR[i] = rsqrtf(var + 1e-5f);
      }
    }
    __syncthreads();
#pragma unroll
    for (int i = 0; i < 8; ++i) {
      float yv = y[i][t];
      float o_ = (yv - statM[i]) * statR[i] * g[t] + be[t];
      out[((size_t)(b * 1024 + i0 + i)) * 256 + t] = fmaxf(o_, 0.f);
    }
  } else {
#pragma unroll
    for (int rr = 0; rr < 2; ++rr) {
      int i = (rr << 2) + hID;
      float v = 0.25f * (y[i][l] + y[i][64 + l] + y[i][128 + l] + y[i][192 + l]);
      float s = v, q = v * v;
      for (int o = 32; o; o >>= 1) { s += __shfl_xor(s, o); q += __shfl_xor(q, o); }
      float mean = s * (1.f / 64.f);
      float var = q * (1.f / 64.f) - mean * mean;
      float rstd = rsqrtf(var + 1e-5f);
      float o_ = (v - mean) * rstd * g[l] + be[l];
      out[((size_t)(b * 1024 + i0 + i)) * 64 + l] = fmaxf(o_, 0.f);
    }
  }
}

// ---------------------------------------------------------------------------
__global__ __launch_bounds__(256) void k_myemb(
    const float* __restrict__ h2, const int* __restrict__ idx,
    const float* __restrict__ Wm, const float* __restrict__ bm, float* __restrict__ out)
{
  __shared__ float row[64];
  int t = threadIdx.x;
  for (int b = 0; b < 8; ++b) {
    int n = idx[b];
    if (t < 64) row[t] = h2[((size_t)(b * 1024 + n)) * 64 + t];
    __syncthreads();
    float acc = bm[t];
#pragma unroll
    for (int d = 0; d < 64; ++d) acc += row[d] * Wm[d * 256 + t];
    out[2097152 + b * 256 + t] = fmaxf(acc, 0.f);
    __syncthreads();
  }
}

// ---------------------------------------------------------------------------
extern "C" void kernel_launch(void* const* d_in, const int* in_sizes, int n_in,
                              void* d_out, int out_size, void* d_ws, size_t ws_size,
                              hipStream_t stream) {
  const float* agents = (const float*)d_in[0];
  const int* my_id = (const int*)d_in[1];
  const float* Wp = (const float*)d_in[2];
  const float* bp = (const float*)d_in[3];
  const float* W1 = (const float*)d_in[4];
  const float* a_src1 = (const float*)d_in[5];
  const float* a_dst1 = (const float*)d_in[6];
  const float* ln1_g = (const float*)d_in[7];
  const float* ln1_b = (const float*)d_in[8];
  const float* W2 = (const float*)d_in[9];
  const float* a_src2 = (const float*)d_in[10];
  const float* a_dst2 = (const float*)d_in[11];
  const float* ln2_g = (const float*)d_in[12];
  const float* ln2_b = (const float*)d_in[13];
  const float* Wa = (const float*)d_in[14];
  const float* ba = (const float*)d_in[15];
  const float* Wm = (const float*)d_in[16];
  const float* bm = (const float*)d_in[17];
  float* out = (float*)d_out;

  float* W = (float*)d_ws;
  float* mask = W;                    // 8192
  float* Mmax = W + 8192;             // 32
  int* idx = (int*)(W + 8224);        // 8 ints
  float* esrc = W + 16384;            // 32768  [B][H][N]
  float* edst = W + 49152;            // 32768
  float* proj = W + 81920;            // 2097152
  float* htmp = W + 2179072;          // 2097152
  float* h1 = W + 4276224;            // 2097152
  float* h2 = W + 6373376;            // 524288
  float* pacc = W + 6897664;          // 4194304  [JS=2][8][128][8][256]
  float* psp = W + 11091968;          // 65536    [JS=2][8][128][8][4]

  hipMemsetAsync(idx, 0x7F, 8 * sizeof(int), stream);
  k_proj<<<8192, 256, 0, stream>>>(agents, my_id, Wp, bp, proj, mask, idx);

  // ---- layer 1 ----
  k_gemm<<<512, 256, 0, stream>>>(proj, W1, nullptr, htmp, 256);
  k_edges<<<2048, 256, 0, stream>>>(htmp, a_src1, a_dst1, esrc, edst);
  k_emax<<<32, 256, 0, stream>>>(edst, mask, Mmax);
  k_attn_part<2><<<2048, 256, 0, stream>>>(htmp, esrc, edst, Mmax, mask, pacc, psp);
  k_attn_epi<1, 2><<<1024, 256, 0, stream>>>(pacc, psp, proj, ln1_g, ln1_b, h1);

  // ---- layer 2 ----
  k_gemm<<<512, 256, 0, stream>>>(h1, W2, nullptr, htmp, 256);
  k_edges<<<2048, 256, 0, stream>>>(htmp, a_src2, a_dst2, esrc, edst);
  k_emax<<<32, 256, 0, stream>>>(edst, mask, Mmax);
  k_attn_part<2><<<2048, 256, 0, stream>>>(htmp, esrc, edst, Mmax, mask, pacc, psp);
  k_attn_epi<2, 2><<<1024, 256, 0, stream>>>(pacc, psp, nullptr, ln2_g, ln2_b, h2);

  // ---- heads ----
  k_gemm<<<512, 256, 0, stream>>>(h2, Wa, ba, out, 64);
  k_myemb<<<1, 256, 0, stream>>>(h2, idx, Wm, bm, out);
}

// Round 8
// 388.092 us; speedup vs baseline: 1.4189x; 1.4189x over previous
//
#include <hip/hip_runtime.h>
#include <hip/hip_bf16.h>

// Sizes (fixed by the problem)
// B=8, N=1024, hidden=256, heads H=4, d_head D=64, entity_dim=31, merged=35

// ---------------------------------------------------------------------------
// k_proj: merged one-hot projection + mask + my-idx
__global__ __launch_bounds__(256) void k_proj(
    const float* __restrict__ agents, const int* __restrict__ my_id,
    const float* __restrict__ Wp, const float* __restrict__ bp,
    float* __restrict__ proj, float* __restrict__ mask, int* __restrict__ idx)
{
  int blk = blockIdx.x;
  int b = blk >> 10, n = blk & 1023;
  __shared__ float arow[32];
  int t = threadIdx.x;
  if (t < 31) arow[t] = agents[((size_t)(b * 1024 + n)) * 31 + t];
  __syncthreads();
  float id = arow[0];
  int npc = (int)arow[1];
  float acc = bp[t] + id * Wp[t] + Wp[(1 + npc) * 256 + t];
#pragma unroll
  for (int c = 2; c < 31; ++c) acc += arow[c] * Wp[(4 + c) * 256 + t];
  proj[((size_t)(b * 1024 + n)) * 256 + t] = acc;
  if (t == 0) {
    mask[b * 1024 + n] = (id != 0.f) ? 1.f : 0.f;
    if (id == (float)my_id[b]) atomicMin(&idx[b], n);
  }
}

// ---------------------------------------------------------------------------
// Generic fp32 GEMM: C[M x 256] = A[M x K] * B[K x 256] (+bias), M = 8192
__global__ __launch_bounds__(256) void k_gemm(
    const float* __restrict__ A, const float* __restrict__ B,
    const float* __restrict__ bias, float* __restrict__ C, int K)
{
  __shared__ float As[64][68];  // [k][i]
  __shared__ float Bs[64][68];  // [k][j]
  int tid = threadIdx.x;
  int bi = blockIdx.x >> 2;   // 0..127
  int bj = blockIdx.x & 3;    // 0..3
  int i0 = bi << 6, j0 = bj << 6;
  int ti4 = (tid & 15) << 2;
  int tj4 = (tid >> 4) << 2;
  int r = tid >> 2;
  int c0 = (tid & 3) << 4;
  float acc[4][4];
#pragma unroll
  for (int a = 0; a < 4; ++a)
#pragma unroll
    for (int q = 0; q < 4; ++q) acc[a][q] = 0.f;

  for (int k0 = 0; k0 < K; k0 += 64) {
    const float4* Ap4 = (const float4*)(A + (size_t)(i0 + r) * K + k0 + c0);
    float4 aa0 = Ap4[0], aa1 = Ap4[1], aa2 = Ap4[2], aa3 = Ap4[3];
    As[c0 + 0][r] = aa0.x; As[c0 + 1][r] = aa0.y; As[c0 + 2][r] = aa0.z; As[c0 + 3][r] = aa0.w;
    As[c0 + 4][r] = aa1.x; As[c0 + 5][r] = aa1.y; As[c0 + 6][r] = aa1.z; As[c0 + 7][r] = aa1.w;
    As[c0 + 8][r] = aa2.x; As[c0 + 9][r] = aa2.y; As[c0 +10][r] = aa2.z; As[c0 +11][r] = aa2.w;
    As[c0 +12][r] = aa3.x; As[c0 +13][r] = aa3.y; As[c0 +14][r] = aa3.z; As[c0 +15][r] = aa3.w;
    const float4* Bp4 = (const float4*)(B + (size_t)(k0 + r) * 256 + j0 + c0);
    float4 bb0 = Bp4[0], bb1 = Bp4[1], bb2 = Bp4[2], bb3 = Bp4[3];
    *(float4*)&Bs[r][c0 + 0]  = bb0;
    *(float4*)&Bs[r][c0 + 4]  = bb1;
    *(float4*)&Bs[r][c0 + 8]  = bb2;
    *(float4*)&Bs[r][c0 + 12] = bb3;
    __syncthreads();
#pragma unroll
    for (int k = 0; k < 64; ++k) {
      float4 av = *(const float4*)&As[k][ti4];
      float4 bv = *(const float4*)&Bs[k][tj4];
      acc[0][0] += av.x * bv.x; acc[0][1] += av.x * bv.y; acc[0][2] += av.x * bv.z; acc[0][3] += av.x * bv.w;
      acc[1][0] += av.y * bv.x; acc[1][1] += av.y * bv.y; acc[1][2] += av.y * bv.z; acc[1][3] += av.y * bv.w;
      acc[2][0] += av.z * bv.x; acc[2][1] += av.z * bv.y; acc[2][2] += av.z * bv.z; acc[2][3] += av.z * bv.w;
      acc[3][0] += av.w * bv.x; acc[3][1] += av.w * bv.y; acc[3][2] += av.w * bv.z; acc[3][3] += av.w * bv.w;
    }
    __syncthreads();
  }
  float4 bb;
  if (bias) bb = *(const float4*)&bias[j0 + tj4];
  else { bb.x = bb.y = bb.z = bb.w = 0.f; }
#pragma unroll
  for (int ii = 0; ii < 4; ++ii) {
    float4 o;
    o.x = acc[ii][0] + bb.x; o.y = acc[ii][1] + bb.y;
    o.z = acc[ii][2] + bb.z; o.w = acc[ii][3] + bb.w;
    *(float4*)&C[(size_t)(i0 + ti4 + ii) * 256 + j0 + tj4] = o;
  }
}

// ---------------------------------------------------------------------------
// k_edges: e_src/e_dst [B][H][N]
__global__ __launch_bounds__(256) void k_edges(
    const float* __restrict__ h, const float* __restrict__ a_src,
    const float* __restrict__ a_dst, float* __restrict__ esrc, float* __restrict__ edst)
{
  __shared__ float as_[256], ad_[256];
  int t = threadIdx.x;
  as_[t] = a_src[t];
  ad_[t] = a_dst[t];
  __syncthreads();
  int w = t >> 6, l = t & 63;
  int row = blockIdx.x * 4 + w;
  const float* x = h + (size_t)row * 256;
  float ps[4], pd[4];
#pragma unroll
  for (int hh = 0; hh < 4; ++hh) {
    float v = x[hh * 64 + l];
    ps[hh] = v * as_[hh * 64 + l];
    pd[hh] = v * ad_[hh * 64 + l];
  }
#pragma unroll
  for (int hh = 0; hh < 4; ++hh) {
    for (int o = 32; o; o >>= 1) {
      ps[hh] += __shfl_down(ps[hh], o);
      pd[hh] += __shfl_down(pd[hh], o);
    }
  }
  if (l == 0) {
    int b = row >> 10, n = row & 1023;
#pragma unroll
    for (int hh = 0; hh < 4; ++hh) {
      esrc[((b * 4 + hh) << 10) + n] = ps[hh];
      edst[((b * 4 + hh) << 10) + n] = pd[hh];
    }
  }
}

// ---------------------------------------------------------------------------
__global__ __launch_bounds__(256) void k_emax(
    const float* __restrict__ edst, const float* __restrict__ mask, float* __restrict__ Mmax)
{
  int bh = blockIdx.x;
  int b = bh >> 2;
  int t = threadIdx.x;
  float v = -1e30f;
  for (int j = t; j < 1024; j += 256)
    if (mask[(b << 10) + j] != 0.f) v = fmaxf(v, edst[(bh << 10) + j]);
  for (int o = 32; o; o >>= 1) v = fmaxf(v, __shfl_down(v, o));
  __shared__ float red[4];
  if ((t & 63) == 0) red[t >> 6] = v;
  __syncthreads();
  if (t == 0) Mmax[bh] = fmaxf(fmaxf(red[0], red[1]), fmaxf(red[2], red[3]));
}

// ---------------------------------------------------------------------------
// k_attn_part: pass A — unnormalized partial aggregation over a j-slice.
// ITILE=8, JS=2 j-slices -> grid = 2048 blocks = 8 blocks/CU.
// NOTE: plain __launch_bounds__(256) — the (256,8) hint in the previous round
// capped VGPRs at 32 and spilled acc[8][4] to scratch (382 MB/dispatch of
// spill traffic). Body compiles to ~52 VGPR naturally, which still permits
// 8 waves/SIMD (occupancy steps at 64 VGPR).
template <int JS>
__global__ __launch_bounds__(256) void k_attn_part(
    const float* __restrict__ h, const float* __restrict__ esrc,
    const float* __restrict__ edst, const float* __restrict__ Mmax,
    const float* __restrict__ mask,
    float* __restrict__ pacc, float* __restrict__ psp)
{
  __shared__ float wT[4][64][12];  // [h][j][i], row = 48B
  __shared__ float esrcL[8][4], mL[8][4];
  __shared__ float maskL[8], MhL[4];

  int t = threadIdx.x;
  int hID = t >> 6, l = t & 63;
  int jq = l >> 4;           // j quarter 0..3
  int dq = (l & 15) << 2;    // d offset 0,4,...,60
  int b = blockIdx.x & 7;    // one b per XCD
  int rem = blockIdx.x >> 3;
  int it = rem & 127;        // i-tile 0..127
  int js = rem >> 7;         // j-slice 0..JS-1
  int i0 = it << 3;
  const int NC = (1024 / JS) >> 6;  // 64-wide chunks per slice
  int jbase = js * (1024 / JS);

  if (t < 8) maskL[t] = mask[(b << 10) + i0 + t];
  if (t < 4) MhL[t] = Mmax[(b << 2) + t];
  if (t < 32) {
    int ii = t >> 2, hh = t & 3;
    esrcL[ii][hh] = esrc[(((b << 2) + hh) << 10) + i0 + ii];
  }
  __syncthreads();
  if (t < 32) {
    int ii = t >> 2, hh = t & 3;
    float m = 0.f;
    if (maskL[ii] != 0.f) {
      float v = esrcL[ii][hh] + MhL[hh];
      m = v > 0.f ? v : 0.2f * v;
    }
    mL[ii][hh] = m;
  }
  __syncthreads();

  float esr[8], mr[8], mskr[8];
#pragma unroll
  for (int i = 0; i < 8; ++i) {
    esr[i] = esrcL[i][hID];
    mr[i] = mL[i][hID];
    mskr[i] = maskL[i];
  }

  float acc[8][4];
  float sp[8];
#pragma unroll
  for (int i = 0; i < 8; ++i) {
    sp[i] = 0.f;
#pragma unroll
    for (int q = 0; q < 4; ++q) acc[i][q] = 0.f;
  }

  const float* ej_base = edst + (((b << 2) + hID) << 10) + jbase;
  const float* mk_base = mask + (b << 10) + jbase;
  const float* h_base = h + ((size_t)((b << 10) + jbase)) * 256 + (hID << 6) + dq;

  for (int c = 0; c < NC; ++c) {
    int j0 = c << 6;
    // ---- weight phase: lane l computes w for j = jbase + j0 + l, 8 rows ----
    float ejv = ej_base[j0 + l];
    float mj = mk_base[j0 + l];
    float w8[8];
#pragma unroll
    for (int i = 0; i < 8; ++i) {
      float w;
      if (mskr[i] != 0.f) {
        float v = esr[i] + ejv;
        v = v > 0.f ? v : 0.2f * v;
        w = (mj != 0.f) ? __expf(v - mr[i]) : 0.f;
      } else {
        w = 1.f;  // invalid row -> uniform over ALL j (matches reference)
      }
      w8[i] = w;
      sp[i] += w;
    }
    *(float4*)&wT[hID][l][0] = *(const float4*)&w8[0];
    *(float4*)&wT[hID][l][4] = *(const float4*)&w8[4];
    __syncthreads();
    // ---- aggregation: thread covers j = j0 + jq + 4s, d = dq..dq+3 ----
    const float* hp = h_base + (size_t)(j0 + jq) * 256;
#pragma unroll 4
    for (int s = 0; s < 16; ++s) {
      float4 hv = *(const float4*)(hp + (size_t)s * 1024);
      int jr = (s << 2) + jq;
      float4 w0 = *(const float4*)&wT[hID][jr][0];
      float4 w1 = *(const float4*)&wT[hID][jr][4];
      acc[0][0] += w0.x * hv.x; acc[0][1] += w0.x * hv.y; acc[0][2] += w0.x * hv.z; acc[0][3] += w0.x * hv.w;
      acc[1][0] += w0.y * hv.x; acc[1][1] += w0.y * hv.y; acc[1][2] += w0.y * hv.z; acc[1][3] += w0.y * hv.w;
      acc[2][0] += w0.z * hv.x; acc[2][1] += w0.z * hv.y; acc[2][2] += w0.z * hv.z; acc[2][3] += w0.z * hv.w;
      acc[3][0] += w0.w * hv.x; acc[3][1] += w0.w * hv.y; acc[3][2] += w0.w * hv.z; acc[3][3] += w0.w * hv.w;
      acc[4][0] += w1.x * hv.x; acc[4][1] += w1.x * hv.y; acc[4][2] += w1.x * hv.z; acc[4][3] += w1.x * hv.w;
      acc[5][0] += w1.y * hv.x; acc[5][1] += w1.y * hv.y; acc[5][2] += w1.y * hv.z; acc[5][3] += w1.y * hv.w;
      acc[6][0] += w1.z * hv.x; acc[6][1] += w1.z * hv.y; acc[6][2] += w1.z * hv.z; acc[6][3] += w1.z * hv.w;
      acc[7][0] += w1.w * hv.x; acc[7][1] += w1.w * hv.y; acc[7][2] += w1.w * hv.z; acc[7][3] += w1.w * hv.w;
    }
    __syncthreads();
  }

  // cross-quarter reduce: lanes l, l^16, l^32, l^48 share (head, d)
#pragma unroll
  for (int i = 0; i < 8; ++i)
#pragma unroll
    for (int q = 0; q < 4; ++q) {
      acc[i][q] += __shfl_xor(acc[i][q], 16);
      acc[i][q] += __shfl_xor(acc[i][q], 32);
    }

  // partial denominators
  size_t pbase = (((size_t)js * 8 + b) * 128 + it) * 8;
#pragma unroll
  for (int i = 0; i < 8; ++i) {
    float v = sp[i];
    for (int o = 32; o; o >>= 1) v += __shfl_xor(v, o);
    if (l == 0) psp[(pbase + i) * 4 + hID] = v;
  }

  // write unnormalized partial aggregation (one writer per column)
  if (jq == 0) {
#pragma unroll
    for (int i = 0; i < 8; ++i) {
      float4 o;
      o.x = acc[i][0]; o.y = acc[i][1]; o.z = acc[i][2]; o.w = acc[i][3];
      *(float4*)&pacc[(pbase + i) * 256 + (hID << 6) + dq] = o;
    }
  }
}

// ---------------------------------------------------------------------------
// k_attn_epi: pass B — combine JS partials, normalize, resid/LN/relu.
// grid = 1024 blocks (b = blk & 7 keeps pacc reads XCD-local).
template <int LAYER, int JS>
__global__ __launch_bounds__(256) void k_attn_epi(
    const float* __restrict__ pacc, const float* __restrict__ psp,
    const float* __restrict__ resid, const float* __restrict__ g,
    const float* __restrict__ be, float* __restrict__ out)
{
  __shared__ float y[8][256];
  __shared__ float sInv[8][4];
  __shared__ float statM[8], statR[8];

  int t = threadIdx.x;
  int hID = t >> 6, l = t & 63;
  int b = blockIdx.x & 7;
  int it = blockIdx.x >> 3;
  int i0 = it << 3;

  if (t < 32) {
    int ii = t >> 2, hh = t & 3;
    float s = 0.f;
#pragma unroll
    for (int js = 0; js < JS; ++js)
      s += psp[((((size_t)js * 8 + b) * 128 + it) * 8 + ii) * 4 + hh];
    sInv[ii][hh] = 1.f / s;
  }
  __syncthreads();

#pragma unroll
  for (int i = 0; i < 8; ++i) {
    float a = 0.f;
#pragma unroll
    for (int js = 0; js < JS; ++js)
      a += pacc[((((size_t)js * 8 + b) * 128 + it) * 8 + i) * 256 + t];
    y[i][t] = a * sInv[i][hID];
  }
  __syncthreads();

  if (LAYER == 1) {
#pragma unroll
    for (int i = 0; i < 8; ++i)
      y[i][t] += resid[((size_t)(b * 1024 + i0 + i)) * 256 + t];
    __syncthreads();
#pragma unroll
    for (int rr = 0; rr < 2; ++rr) {
      int i = (rr << 2) + hID;
      float v0 = y[i][l], v1 = y[i][64 + l], v2 = y[i][128 + l], v3 = y[i][192 + l];
      float s = v0 + v1 + v2 + v3;
      float q = v0 * v0 + v1 * v1 + v2 * v2 + v3 * v3;
      for (int o = 32; o; o >>= 1) { s += __shfl_xor(s, o); q += __shfl_xor(q, o); }
      if (l == 0) {
        float mean = s * (1.f / 256.f);
        float var = q * (1.f / 256.f) - mean * mean;
        statM[i] = mean;
        statR[i] = rsqrtf(var + 1e-5f);
      }
    }
    __syncthreads();
#pragma unroll
    for (int i = 0; i < 8; ++i) {
      float yv = y[i][t];
      float o_ = (yv - statM[i]) * statR[i] * g[t] + be[t];
      out[((size_t)(b * 1024 + i0 + i)) * 256 + t] = fmaxf(o_, 0.f);
    }
  } else {
#pragma unroll
    for (int rr = 0; rr < 2; ++rr) {
      int i = (rr << 2) + hID;
      float v = 0.25f * (y[i][l] + y[i][64 + l] + y[i][128 + l] + y[i][192 + l]);
      float s = v, q = v * v;
      for (int o = 32; o; o >>= 1) { s += __shfl_xor(s, o); q += __shfl_xor(q, o); }
      float mean = s * (1.f / 64.f);
      float var = q * (1.f / 64.f) - mean * mean;
      float rstd = rsqrtf(var + 1e-5f);
      float o_ = (v - mean) * rstd * g[l] + be[l];
      out[((size_t)(b * 1024 + i0 + i)) * 64 + l] = fmaxf(o_, 0.f);
    }
  }
}

// ---------------------------------------------------------------------------
__global__ __launch_bounds__(256) void k_myemb(
    const float* __restrict__ h2, const int* __restrict__ idx,
    const float* __restrict__ Wm, const float* __restrict__ bm, float* __restrict__ out)
{
  __shared__ float row[64];
  int t = threadIdx.x;
  for (int b = 0; b < 8; ++b) {
    int n = idx[b];
    if (t < 64) row[t] = h2[((size_t)(b * 1024 + n)) * 64 + t];
    __syncthreads();
    float acc = bm[t];
#pragma unroll
    for (int d = 0; d < 64; ++d) acc += row[d] * Wm[d * 256 + t];
    out[2097152 + b * 256 + t] = fmaxf(acc, 0.f);
    __syncthreads();
  }
}

// ---------------------------------------------------------------------------
extern "C" void kernel_launch(void* const* d_in, const int* in_sizes, int n_in,
                              void* d_out, int out_size, void* d_ws, size_t ws_size,
                              hipStream_t stream) {
  const float* agents = (const float*)d_in[0];
  const int* my_id = (const int*)d_in[1];
  const float* Wp = (const float*)d_in[2];
  const float* bp = (const float*)d_in[3];
  const float* W1 = (const float*)d_in[4];
  const float* a_src1 = (const float*)d_in[5];
  const float* a_dst1 = (const float*)d_in[6];
  const float* ln1_g = (const float*)d_in[7];
  const float* ln1_b = (const float*)d_in[8];
  const float* W2 = (const float*)d_in[9];
  const float* a_src2 = (const float*)d_in[10];
  const float* a_dst2 = (const float*)d_in[11];
  const float* ln2_g = (const float*)d_in[12];
  const float* ln2_b = (const float*)d_in[13];
  const float* Wa = (const float*)d_in[14];
  const float* ba = (const float*)d_in[15];
  const float* Wm = (const float*)d_in[16];
  const float* bm = (const float*)d_in[17];
  float* out = (float*)d_out;

  float* W = (float*)d_ws;
  float* mask = W;                    // 8192
  float* Mmax = W + 8192;             // 32
  int* idx = (int*)(W + 8224);        // 8 ints
  float* esrc = W + 16384;            // 32768  [B][H][N]
  float* edst = W + 49152;            // 32768
  float* proj = W + 81920;            // 2097152
  float* htmp = W + 2179072;          // 2097152
  float* h1 = W + 4276224;            // 2097152
  float* h2 = W + 6373376;            // 524288
  float* pacc = W + 6897664;          // 4194304  [JS=2][8][128][8][256]
  float* psp = W + 11091968;          // 65536    [JS=2][8][128][8][4]

  hipMemsetAsync(idx, 0x7F, 8 * sizeof(int), stream);
  k_proj<<<8192, 256, 0, stream>>>(agents, my_id, Wp, bp, proj, mask, idx);

  // ---- layer 1 ----
  k_gemm<<<512, 256, 0, stream>>>(proj, W1, nullptr, htmp, 256);
  k_edges<<<2048, 256, 0, stream>>>(htmp, a_src1, a_dst1, esrc, edst);
  k_emax<<<32, 256, 0, stream>>>(edst, mask, Mmax);
  k_attn_part<2><<<2048, 256, 0, stream>>>(htmp, esrc, edst, Mmax, mask, pacc, psp);
  k_attn_epi<1, 2><<<1024, 256, 0, stream>>>(pacc, psp, proj, ln1_g, ln1_b, h1);

  // ---- layer 2 ----
  k_gemm<<<512, 256, 0, stream>>>(h1, W2, nullptr, htmp, 256);
  k_edges<<<2048, 256, 0, stream>>>(htmp, a_src2, a_dst2, esrc, edst);
  k_emax<<<32, 256, 0, stream>>>(edst, mask, Mmax);
  k_attn_part<2><<<2048, 256, 0, stream>>>(htmp, esrc, edst, Mmax, mask, pacc, psp);
  k_attn_epi<2, 2><<<1024, 256, 0, stream>>>(pacc, psp, nullptr, ln2_g, ln2_b, h2);

  // ---- heads ----
  k_gemm<<<512, 256, 0, stream>>>(h2, Wa, ba, out, 64);
  k_myemb<<<1, 256, 0, stream>>>(h2, idx, Wm, bm, out);
}

// Round 11
// 359.841 us; speedup vs baseline: 1.5303x; 1.0785x over previous
//
#include <hip/hip_runtime.h>
#include <hip/hip_bf16.h>

// Sizes (fixed by the problem)
// B=8, N=1024, hidden=256, heads H=4, d_head D=64, entity_dim=31, merged=35

// ---------------------------------------------------------------------------
// k_proj: merged one-hot projection + mask + my-idx
__global__ __launch_bounds__(256) void k_proj(
    const float* __restrict__ agents, const int* __restrict__ my_id,
    const float* __restrict__ Wp, const float* __restrict__ bp,
    float* __restrict__ proj, float* __restrict__ mask, int* __restrict__ idx)
{
  int blk = blockIdx.x;
  int b = blk >> 10, n = blk & 1023;
  __shared__ float arow[32];
  int t = threadIdx.x;
  if (t < 31) arow[t] = agents[((size_t)(b * 1024 + n)) * 31 + t];
  __syncthreads();
  float id = arow[0];
  int npc = (int)arow[1];
  float acc = bp[t] + id * Wp[t] + Wp[(1 + npc) * 256 + t];
#pragma unroll
  for (int c = 2; c < 31; ++c) acc += arow[c] * Wp[(4 + c) * 256 + t];
  proj[((size_t)(b * 1024 + n)) * 256 + t] = acc;
  if (t == 0) {
    mask[b * 1024 + n] = (id != 0.f) ? 1.f : 0.f;
    if (id == (float)my_id[b]) atomicMin(&idx[b], n);
  }
}

// ---------------------------------------------------------------------------
// Generic fp32 GEMM: C[M x 256] = A[M x K] * B[K x 256] (+bias), M = 8192
__global__ __launch_bounds__(256) void k_gemm(
    const float* __restrict__ A, const float* __restrict__ B,
    const float* __restrict__ bias, float* __restrict__ C, int K)
{
  __shared__ float As[64][68];  // [k][i]
  __shared__ float Bs[64][68];  // [k][j]
  int tid = threadIdx.x;
  int bi = blockIdx.x >> 2;   // 0..127
  int bj = blockIdx.x & 3;    // 0..3
  int i0 = bi << 6, j0 = bj << 6;
  int ti4 = (tid & 15) << 2;
  int tj4 = (tid >> 4) << 2;
  int r = tid >> 2;
  int c0 = (tid & 3) << 4;
  float acc[4][4];
#pragma unroll
  for (int a = 0; a < 4; ++a)
#pragma unroll
    for (int q = 0; q < 4; ++q) acc[a][q] = 0.f;

  for (int k0 = 0; k0 < K; k0 += 64) {
    const float4* Ap4 = (const float4*)(A + (size_t)(i0 + r) * K + k0 + c0);
    float4 aa0 = Ap4[0], aa1 = Ap4[1], aa2 = Ap4[2], aa3 = Ap4[3];
    As[c0 + 0][r] = aa0.x; As[c0 + 1][r] = aa0.y; As[c0 + 2][r] = aa0.z; As[c0 + 3][r] = aa0.w;
    As[c0 + 4][r] = aa1.x; As[c0 + 5][r] = aa1.y; As[c0 + 6][r] = aa1.z; As[c0 + 7][r] = aa1.w;
    As[c0 + 8][r] = aa2.x; As[c0 + 9][r] = aa2.y; As[c0 +10][r] = aa2.z; As[c0 +11][r] = aa2.w;
    As[c0 +12][r] = aa3.x; As[c0 +13][r] = aa3.y; As[c0 +14][r] = aa3.z; As[c0 +15][r] = aa3.w;
    const float4* Bp4 = (const float4*)(B + (size_t)(k0 + r) * 256 + j0 + c0);
    float4 bb0 = Bp4[0], bb1 = Bp4[1], bb2 = Bp4[2], bb3 = Bp4[3];
    *(float4*)&Bs[r][c0 + 0]  = bb0;
    *(float4*)&Bs[r][c0 + 4]  = bb1;
    *(float4*)&Bs[r][c0 + 8]  = bb2;
    *(float4*)&Bs[r][c0 + 12] = bb3;
    __syncthreads();
#pragma unroll
    for (int k = 0; k < 64; ++k) {
      float4 av = *(const float4*)&As[k][ti4];
      float4 bv = *(const float4*)&Bs[k][tj4];
      acc[0][0] += av.x * bv.x; acc[0][1] += av.x * bv.y; acc[0][2] += av.x * bv.z; acc[0][3] += av.x * bv.w;
      acc[1][0] += av.y * bv.x; acc[1][1] += av.y * bv.y; acc[1][2] += av.y * bv.z; acc[1][3] += av.y * bv.w;
      acc[2][0] += av.z * bv.x; acc[2][1] += av.z * bv.y; acc[2][2] += av.z * bv.z; acc[2][3] += av.z * bv.w;
      acc[3][0] += av.w * bv.x; acc[3][1] += av.w * bv.y; acc[3][2] += av.w * bv.z; acc[3][3] += av.w * bv.w;
    }
    __syncthreads();
  }
  float4 bb;
  if (bias) bb = *(const float4*)&bias[j0 + tj4];
  else { bb.x = bb.y = bb.z = bb.w = 0.f; }
#pragma unroll
  for (int ii = 0; ii < 4; ++ii) {
    float4 o;
    o.x = acc[ii][0] + bb.x; o.y = acc[ii][1] + bb.y;
    o.z = acc[ii][2] + bb.z; o.w = acc[ii][3] + bb.w;
    *(float4*)&C[(size_t)(i0 + ti4 + ii) * 256 + j0 + tj4] = o;
  }
}

// ---------------------------------------------------------------------------
// k_edges: e_src/e_dst [B][H][N]
__global__ __launch_bounds__(256) void k_edges(
    const float* __restrict__ h, const float* __restrict__ a_src,
    const float* __restrict__ a_dst, float* __restrict__ esrc, float* __restrict__ edst)
{
  __shared__ float as_[256], ad_[256];
  int t = threadIdx.x;
  as_[t] = a_src[t];
  ad_[t] = a_dst[t];
  __syncthreads();
  int w = t >> 6, l = t & 63;
  int row = blockIdx.x * 4 + w;
  const float* x = h + (size_t)row * 256;
  float ps[4], pd[4];
#pragma unroll
  for (int hh = 0; hh < 4; ++hh) {
    float v = x[hh * 64 + l];
    ps[hh] = v * as_[hh * 64 + l];
    pd[hh] = v * ad_[hh * 64 + l];
  }
#pragma unroll
  for (int hh = 0; hh < 4; ++hh) {
    for (int o = 32; o; o >>= 1) {
      ps[hh] += __shfl_down(ps[hh], o);
      pd[hh] += __shfl_down(pd[hh], o);
    }
  }
  if (l == 0) {
    int b = row >> 10, n = row & 1023;
#pragma unroll
    for (int hh = 0; hh < 4; ++hh) {
      esrc[((b * 4 + hh) << 10) + n] = ps[hh];
      edst[((b * 4 + hh) << 10) + n] = pd[hh];
    }
  }
}

// ---------------------------------------------------------------------------
__global__ __launch_bounds__(256) void k_emax(
    const float* __restrict__ edst, const float* __restrict__ mask, float* __restrict__ Mmax)
{
  int bh = blockIdx.x;
  int b = bh >> 2;
  int t = threadIdx.x;
  float v = -1e30f;
  for (int j = t; j < 1024; j += 256)
    if (mask[(b << 10) + j] != 0.f) v = fmaxf(v, edst[(bh << 10) + j]);
  for (int o = 32; o; o >>= 1) v = fmaxf(v, __shfl_down(v, o));
  __shared__ float red[4];
  if ((t & 63) == 0) red[t >> 6] = v;
  __syncthreads();
  if (t == 0) Mmax[bh] = fmaxf(fmaxf(red[0], red[1]), fmaxf(red[2], red[3]));
}

// ---------------------------------------------------------------------------
// k_attn: fused attention aggregation + epilogue. Single pass, ITILE=8,
// grid = 1024, b = blockIdx.x & 7 (XCD-pinned).
// KEY CHANGE vs R6/R8: NO barriers in the chunk loop. wT[hID] is written and
// read only by wave hID (intra-wave LDS communication, in-order per wave), so
// the two per-chunk __syncthreads were pure convoy overhead — every wave
// stalled on the block's slowest dependent ej-load 32x per block. Waves now
// stream all 16 chunks independently; next chunk's ej/mj are prefetched under
// the current chunk's FMA stream.
template <int LAYER>
__global__ __launch_bounds__(256) void k_attn(
    const float* __restrict__ h, const float* __restrict__ esrc,
    const float* __restrict__ edst, const float* __restrict__ Mmax,
    const float* __restrict__ mask, const float* __restrict__ resid,
    const float* __restrict__ g, const float* __restrict__ be,
    float* __restrict__ out)
{
  __shared__ float wT[4][64][12];  // [h][j][i], row = 48B; per-wave private
  __shared__ float y[8][256];
  __shared__ float esrcL[8][4], mL[8][4], sInv[8][4];
  __shared__ float maskL[8], MhL[4];
  __shared__ float statM[8], statR[8];

  int t = threadIdx.x;
  int hID = t >> 6, l = t & 63;
  int jq = l >> 4;           // j quarter 0..3
  int dq = (l & 15) << 2;    // d offset 0,4,...,60
  int b = blockIdx.x & 7;    // one b per XCD
  int it = blockIdx.x >> 3;  // 0..127
  int i0 = it << 3;

  if (t < 8) maskL[t] = mask[(b << 10) + i0 + t];
  if (t < 4) MhL[t] = Mmax[(b << 2) + t];
  if (t < 32) {
    int ii = t >> 2, hh = t & 3;
    esrcL[ii][hh] = esrc[(((b << 2) + hh) << 10) + i0 + ii];
  }
  __syncthreads();
  if (t < 32) {
    int ii = t >> 2, hh = t & 3;
    float m = 0.f;
    if (maskL[ii] != 0.f) {
      float v = esrcL[ii][hh] + MhL[hh];
      m = v > 0.f ? v : 0.2f * v;
    }
    mL[ii][hh] = m;
  }
  __syncthreads();

  float esr[8], mr[8], mskr[8];
#pragma unroll
  for (int i = 0; i < 8; ++i) {
    esr[i] = esrcL[i][hID];
    mr[i] = mL[i][hID];
    mskr[i] = maskL[i];
  }

  float acc[8][4];
  float sp[8];
#pragma unroll
  for (int i = 0; i < 8; ++i) {
    sp[i] = 0.f;
#pragma unroll
    for (int q = 0; q < 4; ++q) acc[i][q] = 0.f;
  }

  const float* ej_base = edst + (((b << 2) + hID) << 10);
  const float* mk_base = mask + (b << 10);
  const float* h_base = h + ((size_t)(b << 10)) * 256 + (hID << 6) + dq;

  // prefetched edge/mask values for the current chunk
  float ejv = ej_base[l];
  float mj = mk_base[l];

  for (int c = 0; c < 16; ++c) {
    // ---- weight phase (wave-private): lane l -> j = c*64 + l, all 8 rows ----
    float w8[8];
#pragma unroll
    for (int i = 0; i < 8; ++i) {
      float w;
      if (mskr[i] != 0.f) {
        float v = esr[i] + ejv;
        v = v > 0.f ? v : 0.2f * v;
        w = (mj != 0.f) ? __expf(v - mr[i]) : 0.f;
      } else {
        w = 1.f;  // invalid row -> uniform over ALL j (matches reference)
      }
      w8[i] = w;
      sp[i] += w;
    }
    *(float4*)&wT[hID][l][0] = *(const float4*)&w8[0];
    *(float4*)&wT[hID][l][4] = *(const float4*)&w8[4];
    // prefetch next chunk's edge/mask (hidden under the FMA stream below)
    if (c < 15) {
      ejv = ej_base[(c + 1) * 64 + l];
      mj = mk_base[(c + 1) * 64 + l];
    }
    // ---- aggregation (wave-private): j = c*64 + jq + 4s, d = dq..dq+3 ----
    const float* hp = h_base + (size_t)(c * 64 + jq) * 256;
#pragma unroll 4
    for (int s = 0; s < 16; ++s) {
      float4 hv = *(const float4*)(hp + (size_t)s * 1024);
      int jr = (s << 2) + jq;
      float4 w0 = *(const float4*)&wT[hID][jr][0];
      float4 w1 = *(const float4*)&wT[hID][jr][4];
      acc[0][0] += w0.x * hv.x; acc[0][1] += w0.x * hv.y; acc[0][2] += w0.x * hv.z; acc[0][3] += w0.x * hv.w;
      acc[1][0] += w0.y * hv.x; acc[1][1] += w0.y * hv.y; acc[1][2] += w0.y * hv.z; acc[1][3] += w0.y * hv.w;
      acc[2][0] += w0.z * hv.x; acc[2][1] += w0.z * hv.y; acc[2][2] += w0.z * hv.z; acc[2][3] += w0.z * hv.w;
      acc[3][0] += w0.w * hv.x; acc[3][1] += w0.w * hv.y; acc[3][2] += w0.w * hv.z; acc[3][3] += w0.w * hv.w;
      acc[4][0] += w1.x * hv.x; acc[4][1] += w1.x * hv.y; acc[4][2] += w1.x * hv.z; acc[4][3] += w1.x * hv.w;
      acc[5][0] += w1.y * hv.x; acc[5][1] += w1.y * hv.y; acc[5][2] += w1.y * hv.z; acc[5][3] += w1.y * hv.w;
      acc[6][0] += w1.z * hv.x; acc[6][1] += w1.z * hv.y; acc[6][2] += w1.z * hv.z; acc[6][3] += w1.z * hv.w;
      acc[7][0] += w1.w * hv.x; acc[7][1] += w1.w * hv.y; acc[7][2] += w1.w * hv.z; acc[7][3] += w1.w * hv.w;
    }
    // no barrier: wT[hID] is only touched by this wave, in-order LDS ops
  }

  // cross-quarter reduce: lanes l, l^16, l^32, l^48 share (head, d)
#pragma unroll
  for (int i = 0; i < 8; ++i)
#pragma unroll
    for (int q = 0; q < 4; ++q) {
      acc[i][q] += __shfl_xor(acc[i][q], 16);
      acc[i][q] += __shfl_xor(acc[i][q], 32);
    }

  // softmax denominators
#pragma unroll
  for (int i = 0; i < 8; ++i) {
    float v = sp[i];
    for (int o = 32; o; o >>= 1) v += __shfl_xor(v, o);
    if (l == 0) sInv[i][hID] = 1.f / v;
  }
  __syncthreads();

  // write normalized aggregation into y (one writer per column: jq==0 lanes)
  if (jq == 0) {
#pragma unroll
    for (int i = 0; i < 8; ++i) {
      float sv = sInv[i][hID];
      float4 o;
      o.x = acc[i][0] * sv; o.y = acc[i][1] * sv;
      o.z = acc[i][2] * sv; o.w = acc[i][3] * sv;
      *(float4*)&y[i][(hID << 6) + dq] = o;
    }
  }
  __syncthreads();

  if (LAYER == 1) {
#pragma unroll
    for (int i = 0; i < 8; ++i)
      y[i][t] += resid[((size_t)(b * 1024 + i0 + i)) * 256 + t];
    __syncthreads();
#pragma unroll
    for (int rr = 0; rr < 2; ++rr) {
      int i = (rr << 2) + hID;
      float v0 = y[i][l], v1 = y[i][64 + l], v2 = y[i][128 + l], v3 = y[i][192 + l];
      float s = v0 + v1 + v2 + v3;
      float q = v0 * v0 + v1 * v1 + v2 * v2 + v3 * v3;
      for (int o = 32; o; o >>= 1) { s += __shfl_xor(s, o); q += __shfl_xor(q, o); }
      if (l == 0) {
        float mean = s * (1.f / 256.f);
        float var = q * (1.f / 256.f) - mean * mean;
        statM[i] = mean;
        statR[i] = rsqrtf(var + 1e-5f);
      }
    }
    __syncthreads();
#pragma unroll
    for (int i = 0; i < 8; ++i) {
      float yv = y[i][t];
      float o_ = (yv - statM[i]) * statR[i] * g[t] + be[t];
      out[((size_t)(b * 1024 + i0 + i)) * 256 + t] = fmaxf(o_, 0.f);
    }
  } else {
#pragma unroll
    for (int rr = 0; rr < 2; ++rr) {
      int i = (rr << 2) + hID;
      float v = 0.25f * (y[i][l] + y[i][64 + l] + y[i][128 + l] + y[i][192 + l]);
      float s = v, q = v * v;
      for (int o = 32; o; o >>= 1) { s += __shfl_xor(s, o); q += __shfl_xor(q, o); }
      float mean = s * (1.f / 64.f);
      float var = q * (1.f / 64.f) - mean * mean;
      float rstd = rsqrtf(var + 1e-5f);
      float o_ = (v - mean) * rstd * g[l] + be[l];
      out[((size_t)(b * 1024 + i0 + i)) * 64 + l] = fmaxf(o_, 0.f);
    }
  }
}

// ---------------------------------------------------------------------------
__global__ __launch_bounds__(256) void k_myemb(
    const float* __restrict__ h2, const int* __restrict__ idx,
    const float* __restrict__ Wm, const float* __restrict__ bm, float* __restrict__ out)
{
  __shared__ float row[64];
  int t = threadIdx.x;
  for (int b = 0; b < 8; ++b) {
    int n = idx[b];
    if (t < 64) row[t] = h2[((size_t)(b * 1024 + n)) * 64 + t];
    __syncthreads();
    float acc = bm[t];
#pragma unroll
    for (int d = 0; d < 64; ++d) acc += row[d] * Wm[d * 256 + t];
    out[2097152 + b * 256 + t] = fmaxf(acc, 0.f);
    __syncthreads();
  }
}

// ---------------------------------------------------------------------------
extern "C" void kernel_launch(void* const* d_in, const int* in_sizes, int n_in,
                              void* d_out, int out_size, void* d_ws, size_t ws_size,
                              hipStream_t stream) {
  const float* agents = (const float*)d_in[0];
  const int* my_id = (const int*)d_in[1];
  const float* Wp = (const float*)d_in[2];
  const float* bp = (const float*)d_in[3];
  const float* W1 = (const float*)d_in[4];
  const float* a_src1 = (const float*)d_in[5];
  const float* a_dst1 = (const float*)d_in[6];
  const float* ln1_g = (const float*)d_in[7];
  const float* ln1_b = (const float*)d_in[8];
  const float* W2 = (const float*)d_in[9];
  const float* a_src2 = (const float*)d_in[10];
  const float* a_dst2 = (const float*)d_in[11];
  const float* ln2_g = (const float*)d_in[12];
  const float* ln2_b = (const float*)d_in[13];
  const float* Wa = (const float*)d_in[14];
  const float* ba = (const float*)d_in[15];
  const float* Wm = (const float*)d_in[16];
  const float* bm = (const float*)d_in[17];
  float* out = (float*)d_out;

  float* W = (float*)d_ws;
  float* mask = W;                    // 8192
  float* Mmax = W + 8192;             // 32
  int* idx = (int*)(W + 8224);        // 8 ints
  float* esrc = W + 16384;            // 32768  [B][H][N]
  float* edst = W + 49152;            // 32768
  float* proj = W + 81920;            // 2097152
  float* htmp = W + 2179072;          // 2097152
  float* h1 = W + 4276224;            // 2097152
  float* h2 = W + 6373376;            // 524288

  hipMemsetAsync(idx, 0x7F, 8 * sizeof(int), stream);
  k_proj<<<8192, 256, 0, stream>>>(agents, my_id, Wp, bp, proj, mask, idx);

  // ---- layer 1 ----
  k_gemm<<<512, 256, 0, stream>>>(proj, W1, nullptr, htmp, 256);
  k_edges<<<2048, 256, 0, stream>>>(htmp, a_src1, a_dst1, esrc, edst);
  k_emax<<<32, 256, 0, stream>>>(edst, mask, Mmax);
  k_attn<1><<<1024, 256, 0, stream>>>(htmp, esrc, edst, Mmax, mask, proj, ln1_g, ln1_b, h1);

  // ---- layer 2 ----
  k_gemm<<<512, 256, 0, stream>>>(h1, W2, nullptr, htmp, 256);
  k_edges<<<2048, 256, 0, stream>>>(htmp, a_src2, a_dst2, esrc, edst);
  k_emax<<<32, 256, 0, stream>>>(edst, mask, Mmax);
  k_attn<2><<<1024, 256, 0, stream>>>(htmp, esrc, edst, Mmax, mask, proj, ln2_g, ln2_b, h2);

  // ---- heads ----
  k_gemm<<<512, 256, 0, stream>>>(h2, Wa, ba, out, 64);
  k_myemb<<<1, 256, 0, stream>>>(h2, idx, Wm, bm, out);
}

// Round 14
// 243.098 us; speedup vs baseline: 2.2652x; 1.4802x over previous
//
#include <hip/hip_runtime.h>
#include <hip/hip_bf16.h>

// Sizes: B=8, N=1024, hidden=256, H=4 heads, D=64, entity=31
typedef _Float16 f16x8 __attribute__((ext_vector_type(8)));
typedef float f32x4 __attribute__((ext_vector_type(4)));

// ---------------------------------------------------------------------------
__global__ __launch_bounds__(256) void k_proj(
    const float* __restrict__ agents, const int* __restrict__ my_id,
    const float* __restrict__ Wp, const float* __restrict__ bp,
    float* __restrict__ proj, float* __restrict__ mask, int* __restrict__ idx)
{
  int blk = blockIdx.x;
  int b = blk >> 10, n = blk & 1023;
  __shared__ float arow[32];
  int t = threadIdx.x;
  if (t < 31) arow[t] = agents[((size_t)(b * 1024 + n)) * 31 + t];
  __syncthreads();
  float id = arow[0];
  int npc = (int)arow[1];
  float acc = bp[t] + id * Wp[t] + Wp[(1 + npc) * 256 + t];
#pragma unroll
  for (int c = 2; c < 31; ++c) acc += arow[c] * Wp[(4 + c) * 256 + t];
  proj[((size_t)(b * 1024 + n)) * 256 + t] = acc;
  if (t == 0) {
    mask[b * 1024 + n] = (id != 0.f) ? 1.f : 0.f;
    if (id == (float)my_id[b]) atomicMin(&idx[b], n);
  }
}

// ---------------------------------------------------------------------------
__global__ __launch_bounds__(256) void k_gemm(
    const float* __restrict__ A, const float* __restrict__ B,
    const float* __restrict__ bias, float* __restrict__ C, int K)
{
  __shared__ float As[64][68];
  __shared__ float Bs[64][68];
  int tid = threadIdx.x;
  int bi = blockIdx.x >> 2, bj = blockIdx.x & 3;
  int i0 = bi << 6, j0 = bj << 6;
  int ti4 = (tid & 15) << 2, tj4 = (tid >> 4) << 2;
  int r = tid >> 2, c0 = (tid & 3) << 4;
  float acc[4][4];
#pragma unroll
  for (int a = 0; a < 4; ++a)
#pragma unroll
    for (int q = 0; q < 4; ++q) acc[a][q] = 0.f;

  for (int k0 = 0; k0 < K; k0 += 64) {
    const float4* Ap4 = (const float4*)(A + (size_t)(i0 + r) * K + k0 + c0);
    float4 aa0 = Ap4[0], aa1 = Ap4[1], aa2 = Ap4[2], aa3 = Ap4[3];
    As[c0 + 0][r] = aa0.x; As[c0 + 1][r] = aa0.y; As[c0 + 2][r] = aa0.z; As[c0 + 3][r] = aa0.w;
    As[c0 + 4][r] = aa1.x; As[c0 + 5][r] = aa1.y; As[c0 + 6][r] = aa1.z; As[c0 + 7][r] = aa1.w;
    As[c0 + 8][r] = aa2.x; As[c0 + 9][r] = aa2.y; As[c0 +10][r] = aa2.z; As[c0 +11][r] = aa2.w;
    As[c0 +12][r] = aa3.x; As[c0 +13][r] = aa3.y; As[c0 +14][r] = aa3.z; As[c0 +15][r] = aa3.w;
    const float4* Bp4 = (const float4*)(B + (size_t)(k0 + r) * 256 + j0 + c0);
    float4 bb0 = Bp4[0], bb1 = Bp4[1], bb2 = Bp4[2], bb3 = Bp4[3];
    *(float4*)&Bs[r][c0 + 0]  = bb0;
    *(float4*)&Bs[r][c0 + 4]  = bb1;
    *(float4*)&Bs[r][c0 + 8]  = bb2;
    *(float4*)&Bs[r][c0 + 12] = bb3;
    __syncthreads();
#pragma unroll
    for (int k = 0; k < 64; ++k) {
      float4 av = *(const float4*)&As[k][ti4];
      float4 bv = *(const float4*)&Bs[k][tj4];
      acc[0][0] += av.x * bv.x; acc[0][1] += av.x * bv.y; acc[0][2] += av.x * bv.z; acc[0][3] += av.x * bv.w;
      acc[1][0] += av.y * bv.x; acc[1][1] += av.y * bv.y; acc[1][2] += av.y * bv.z; acc[1][3] += av.y * bv.w;
      acc[2][0] += av.z * bv.x; acc[2][1] += av.z * bv.y; acc[2][2] += av.z * bv.z; acc[2][3] += av.z * bv.w;
      acc[3][0] += av.w * bv.x; acc[3][1] += av.w * bv.y; acc[3][2] += av.w * bv.z; acc[3][3] += av.w * bv.w;
    }
    __syncthreads();
  }
  float4 bb;
  if (bias) bb = *(const float4*)&bias[j0 + tj4];
  else { bb.x = bb.y = bb.z = bb.w = 0.f; }
#pragma unroll
  for (int ii = 0; ii < 4; ++ii) {
    float4 o;
    o.x = acc[ii][0] + bb.x; o.y = acc[ii][1] + bb.y;
    o.z = acc[ii][2] + bb.z; o.w = acc[ii][3] + bb.w;
    *(float4*)&C[(size_t)(i0 + ti4 + ii) * 256 + j0 + tj4] = o;
  }
}

// ---------------------------------------------------------------------------
__global__ __launch_bounds__(256) void k_edges(
    const float* __restrict__ h, const float* __restrict__ a_src,
    const float* __restrict__ a_dst, float* __restrict__ esrc, float* __restrict__ edst)
{
  __shared__ float as_[256], ad_[256];
  int t = threadIdx.x;
  as_[t] = a_src[t];
  ad_[t] = a_dst[t];
  __syncthreads();
  int w = t >> 6, l = t & 63;
  int row = blockIdx.x * 4 + w;
  const float* x = h + (size_t)row * 256;
  float ps[4], pd[4];
#pragma unroll
  for (int hh = 0; hh < 4; ++hh) {
    float v = x[hh * 64 + l];
    ps[hh] = v * as_[hh * 64 + l];
    pd[hh] = v * ad_[hh * 64 + l];
  }
#pragma unroll
  for (int hh = 0; hh < 4; ++hh) {
    for (int o = 32; o; o >>= 1) {
      ps[hh] += __shfl_down(ps[hh], o);
      pd[hh] += __shfl_down(pd[hh], o);
    }
  }
  if (l == 0) {
    int b = row >> 10, n = row & 1023;
#pragma unroll
    for (int hh = 0; hh < 4; ++hh) {
      esrc[((b * 4 + hh) << 10) + n] = ps[hh];
      edst[((b * 4 + hh) << 10) + n] = pd[hh];
    }
  }
}

// ---------------------------------------------------------------------------
__global__ __launch_bounds__(256) void k_emax(
    const float* __restrict__ edst, const float* __restrict__ mask, float* __restrict__ Mmax)
{
  int bh = blockIdx.x;
  int b = bh >> 2;
  int t = threadIdx.x;
  float v = -1e30f;
  for (int j = t; j < 1024; j += 256)
    if (mask[(b << 10) + j] != 0.f) v = fmaxf(v, edst[(bh << 10) + j]);
  for (int o = 32; o; o >>= 1) v = fmaxf(v, __shfl_down(v, o));
  __shared__ float red[4];
  if ((t & 63) == 0) red[t >> 6] = v;
  __syncthreads();
  if (t == 0) Mmax[bh] = fmaxf(fmaxf(red[0], red[1]), fmaxf(red[2], red[3]));
}

// ---------------------------------------------------------------------------
// k_prep: h fp32 [B][N][256] -> hT fp16 chunk-tiled [B][H][32 c][64 d][32 j]
// grid = B*H*32 = 1024 blocks.
__global__ __launch_bounds__(256) void k_prep(
    const float* __restrict__ h, _Float16* __restrict__ hT)
{
  int blk = blockIdx.x;
  int c = blk & 31, hh = (blk >> 5) & 3, b = blk >> 7;
  int t = threadIdx.x;
  __shared__ _Float16 tile[32][72];
  {
    int jr = t >> 3, dg = t & 7;
    const float* src = h + ((size_t)(b * 1024 + c * 32 + jr)) * 256 + hh * 64 + dg * 8;
    float4 a = *(const float4*)src;
    float4 b4 = *(const float4*)(src + 4);
    _Float16* tp = &tile[jr][dg * 8];
    tp[0] = (_Float16)a.x;  tp[1] = (_Float16)a.y;  tp[2] = (_Float16)a.z;  tp[3] = (_Float16)a.w;
    tp[4] = (_Float16)b4.x; tp[5] = (_Float16)b4.y; tp[6] = (_Float16)b4.z; tp[7] = (_Float16)b4.w;
  }
  __syncthreads();
  {
    int d = t >> 2, q = t & 3;
    _Float16 o[8];
#pragma unroll
    for (int s = 0; s < 8; ++s) o[s] = tile[q * 8 + s][d];
    _Float16* dst = hT + ((size_t)((b * 4 + hh) * 32 + c)) * 2048 + d * 32 + q * 8;
    *(uint4*)dst = *(const uint4*)o;
  }
}

// ---------------------------------------------------------------------------
// k_attn_mfma: P·h via mfma_f32_16x16x32_f16.
// Block = 4 waves (wave = head), ITILE=16 rows, grid = B*64 = 512, b = blk&7.
// Per wave, per 32-j chunk: 8 exps/lane -> A-frag in regs (lane = row l&15,
// k = (l>>4)*8+t); B-frags = ds_read_b128 from 80B-padded fp16 LDS buffer
// (double-buffered, staged by the wave itself -> NO in-loop barriers).
// Accumulate unnormalized in fp32 C-frags; normalize by 1/sum(w) after.
template <int LAYER>
__global__ __launch_bounds__(256) void k_attn_mfma(
    const _Float16* __restrict__ hT, const float* __restrict__ esrc,
    const float* __restrict__ edst, const float* __restrict__ Mmax,
    const float* __restrict__ mask, const float* __restrict__ resid,
    const float* __restrict__ g, const float* __restrict__ be,
    float* __restrict__ out)
{
  // smem: [4 heads][2 buf][64 d][80 B] = 40960 B; y[16][256] fp32 overlaps after k-loop
  __shared__ __align__(16) char smem[40960];
  __shared__ float esrcL[16][4], mL[16][4];
  __shared__ float maskL[16], MhL[4];
  __shared__ float sInvS[4][16];
  __shared__ float statM[16], statR[16];

  int t = threadIdx.x;
  int hID = t >> 6, l = t & 63;
  int b = blockIdx.x & 7;
  int it = blockIdx.x >> 3;  // 0..63
  int i0 = it << 4;

  if (t < 16) maskL[t] = mask[(b << 10) + i0 + t];
  if (t < 4) MhL[t] = Mmax[(b << 2) + t];
  if (t < 64) {
    int ii = t >> 2, hh = t & 3;
    esrcL[ii][hh] = esrc[(((b << 2) + hh) << 10) + i0 + ii];
  }
  __syncthreads();
  if (t < 64) {
    int ii = t >> 2, hh = t & 3;
    float m = 0.f;
    if (maskL[ii] != 0.f) {
      float v = esrcL[ii][hh] + MhL[hh];
      m = v > 0.f ? v : 0.2f * v;
    }
    mL[ii][hh] = m;
  }
  __syncthreads();

  int iloc = l & 15;
  float esr = esrcL[iloc][hID];
  float mr = mL[iloc][hID];
  float mskI = maskL[iloc];
  int jg = (l >> 4) << 3;  // 0,8,16,24: this lane's j-offset within chunk

  const float* ej_base = edst + (((b << 2) + hID) << 10);
  const float* mk_base = mask + (b << 10);
  const char* gT = (const char*)hT + ((size_t)((b * 4 + hID) * 32)) * 4096;
  char* hb = smem + hID * 10240;  // this wave's buffers

  f32x4 C0 = {0.f,0.f,0.f,0.f}, C1 = C0, C2 = C0, C3 = C0;
  float sp = 0.f;

  // prologue: stage chunk 0 into buf 0 (lane l owns d-row l: 64 B)
  {
    const uint4* gs = (const uint4*)(gT + l * 64);
    uint4 s0 = gs[0], s1 = gs[1], s2 = gs[2], s3 = gs[3];
    uint4* wp = (uint4*)(hb + l * 80);
    wp[0] = s0; wp[1] = s1; wp[2] = s2; wp[3] = s3;
  }
  int cur = 0;

  for (int c = 0; c < 32; ++c) {
    uint4 n0, n1, n2, n3;
    if (c < 31) {
      const uint4* gs = (const uint4*)(gT + (size_t)(c + 1) * 4096 + l * 64);
      n0 = gs[0]; n1 = gs[1]; n2 = gs[2]; n3 = gs[3];
    }
    // ---- weights -> A-frag (lane = row iloc, k-slots jg..jg+7) ----
    int j0 = c << 5;
    float4 e0 = *(const float4*)(ej_base + j0 + jg);
    float4 e1 = *(const float4*)(ej_base + j0 + jg + 4);
    float4 m0 = *(const float4*)(mk_base + j0 + jg);
    float4 m1 = *(const float4*)(mk_base + j0 + jg + 4);
    float w[8];
    float ev[8] = {e0.x, e0.y, e0.z, e0.w, e1.x, e1.y, e1.z, e1.w};
    float mv[8] = {m0.x, m0.y, m0.z, m0.w, m1.x, m1.y, m1.z, m1.w};
    if (mskI != 0.f) {
#pragma unroll
      for (int q = 0; q < 8; ++q) {
        float v = esr + ev[q];
        v = v > 0.f ? v : 0.2f * v;
        w[q] = (mv[q] != 0.f) ? __expf(v - mr) : 0.f;
      }
    } else {
#pragma unroll
      for (int q = 0; q < 8; ++q) w[q] = 1.f;  // invalid row: uniform over ALL j
    }
    f16x8 af;
#pragma unroll
    for (int q = 0; q < 8; ++q) { sp += w[q]; af[q] = (_Float16)w[q]; }
    // ---- B-frags + MFMA (current buffer) ----
    const char* rp = hb + cur * 5120 + (l & 15) * 80 + (l >> 4) * 16;
    f16x8 b0 = *(const f16x8*)(rp);
    f16x8 b1 = *(const f16x8*)(rp + 1280);
    f16x8 b2 = *(const f16x8*)(rp + 2560);
    f16x8 b3 = *(const f16x8*)(rp + 3840);
    C0 = __builtin_amdgcn_mfma_f32_16x16x32_f16(af, b0, C0, 0, 0, 0);
    C1 = __builtin_amdgcn_mfma_f32_16x16x32_f16(af, b1, C1, 0, 0, 0);
    C2 = __builtin_amdgcn_mfma_f32_16x16x32_f16(af, b2, C2, 0, 0, 0);
    C3 = __builtin_amdgcn_mfma_f32_16x16x32_f16(af, b3, C3, 0, 0, 0);
    if (c < 31) {
      uint4* wp = (uint4*)(hb + (cur ^ 1) * 5120 + l * 80);
      wp[0] = n0; wp[1] = n1; wp[2] = n2; wp[3] = n3;
      cur ^= 1;
    }
  }

  // denominators: lane owns row iloc; partners at l^16, l^32
  sp += __shfl_xor(sp, 16);
  sp += __shfl_xor(sp, 32);
  if (l < 16) sInvS[hID][l] = 1.f / sp;
  __syncthreads();  // all waves done with hbuf; sInvS visible

  // normalize + write to y[16][256] (overlapping smem)
  float (*y)[256] = (float (*)[256])smem;
  {
    int rbase = (l >> 4) << 2;
    int col = (hID << 6) + (l & 15);
#pragma unroll
    for (int r = 0; r < 4; ++r) {
      float sv = sInvS[hID][rbase + r];
      y[rbase + r][col +  0] = C0[r] * sv;
      y[rbase + r][col + 16] = C1[r] * sv;
      y[rbase + r][col + 32] = C2[r] * sv;
      y[rbase + r][col + 48] = C3[r] * sv;
    }
  }
  __syncthreads();

  if (LAYER == 1) {
#pragma unroll
    for (int i = 0; i < 16; ++i)
      y[i][t] += resid[((size_t)(b * 1024 + i0 + i)) * 256 + t];
    __syncthreads();
#pragma unroll
    for (int rr = 0; rr < 4; ++rr) {
      int i = (hID << 2) + rr;
      float v0 = y[i][l], v1 = y[i][64 + l], v2 = y[i][128 + l], v3 = y[i][192 + l];
      float s = v0 + v1 + v2 + v3;
      float q = v0 * v0 + v1 * v1 + v2 * v2 + v3 * v3;
      for (int o = 32; o; o >>= 1) { s += __shfl_xor(s, o); q += __shfl_xor(q, o); }
      if (l == 0) {
        float mean = s * (1.f / 256.f);
        float var = q * (1.f / 256.f) - mean * mean;
        statM[i] = mean;
        statR[i] = rsqrtf(var + 1e-5f);
      }
    }
    __syncthreads();
#pragma unroll
    for (int i = 0; i < 16; ++i) {
      float yv = y[i][t];
      float o_ = (yv - statM[i]) * statR[i] * g[t] + be[t];
      out[((size_t)(b * 1024 + i0 + i)) * 256 + t] = fmaxf(o_, 0.f);
    }
  } else {
#pragma unroll
    for (int rr = 0; rr < 4; ++rr) {
      int i = (hID << 2) + rr;
      float v = 0.25f * (y[i][l] + y[i][64 + l] + y[i][128 + l] + y[i][192 + l]);
      float s = v, q = v * v;
      for (int o = 32; o; o >>= 1) { s += __shfl_xor(s, o); q += __shfl_xor(q, o); }
      float mean = s * (1.f / 64.f);
      float var = q * (1.f / 64.f) - mean * mean;
      float rstd = rsqrtf(var + 1e-5f);
      float o_ = (v - mean) * rstd * g[l] + be[l];
      out[((size_t)(b * 1024 + i0 + i)) * 64 + l] = fmaxf(o_, 0.f);
    }
  }
}

// ---------------------------------------------------------------------------
__global__ __launch_bounds__(256) void k_myemb(
    const float* __restrict__ h2, const int* __restrict__ idx,
    const float* __restrict__ Wm, const float* __restrict__ bm, float* __restrict__ out)
{
  __shared__ float row[64];
  int t = threadIdx.x;
  for (int b = 0; b < 8; ++b) {
    int n = idx[b];
    if (t < 64) row[t] = h2[((size_t)(b * 1024 + n)) * 64 + t];
    __syncthreads();
    float acc = bm[t];
#pragma unroll
    for (int d = 0; d < 64; ++d) acc += row[d] * Wm[d * 256 + t];
    out[2097152 + b * 256 + t] = fmaxf(acc, 0.f);
    __syncthreads();
  }
}

// ---------------------------------------------------------------------------
extern "C" void kernel_launch(void* const* d_in, const int* in_sizes, int n_in,
                              void* d_out, int out_size, void* d_ws, size_t ws_size,
                              hipStream_t stream) {
  const float* agents = (const float*)d_in[0];
  const int* my_id = (const int*)d_in[1];
  const float* Wp = (const float*)d_in[2];
  const float* bp = (const float*)d_in[3];
  const float* W1 = (const float*)d_in[4];
  const float* a_src1 = (const float*)d_in[5];
  const float* a_dst1 = (const float*)d_in[6];
  const float* ln1_g = (const float*)d_in[7];
  const float* ln1_b = (const float*)d_in[8];
  const float* W2 = (const float*)d_in[9];
  const float* a_src2 = (const float*)d_in[10];
  const float* a_dst2 = (const float*)d_in[11];
  const float* ln2_g = (const float*)d_in[12];
  const float* ln2_b = (const float*)d_in[13];
  const float* Wa = (const float*)d_in[14];
  const float* ba = (const float*)d_in[15];
  const float* Wm = (const float*)d_in[16];
  const float* bm = (const float*)d_in[17];
  float* out = (float*)d_out;

  float* W = (float*)d_ws;
  float* mask = W;                    // 8192
  float* Mmax = W + 8192;             // 32
  int* idx = (int*)(W + 8224);        // 8 ints
  float* esrc = W + 16384;            // 32768  [B][H][N]
  float* edst = W + 49152;            // 32768
  float* proj = W + 81920;            // 2097152
  float* htmp = W + 2179072;          // 2097152
  float* h1 = W + 4276224;            // 2097152
  float* h2 = W + 6373376;            // 524288
  _Float16* hT = (_Float16*)(W + 6897664);  // 2M halfs = 4 MB, chunk-tiled

  hipMemsetAsync(idx, 0x7F, 8 * sizeof(int), stream);
  k_proj<<<8192, 256, 0, stream>>>(agents, my_id, Wp, bp, proj, mask, idx);

  // ---- layer 1 ----
  k_gemm<<<512, 256, 0, stream>>>(proj, W1, nullptr, htmp, 256);
  k_prep<<<1024, 256, 0, stream>>>(htmp, hT);
  k_edges<<<2048, 256, 0, stream>>>(htmp, a_src1, a_dst1, esrc, edst);
  k_emax<<<32, 256, 0, stream>>>(edst, mask, Mmax);
  k_attn_mfma<1><<<512, 256, 0, stream>>>(hT, esrc, edst, Mmax, mask, proj, ln1_g, ln1_b, h1);

  // ---- layer 2 ----
  k_gemm<<<512, 256, 0, stream>>>(h1, W2, nullptr, htmp, 256);
  k_prep<<<1024, 256, 0, stream>>>(htmp, hT);
  k_edges<<<2048, 256, 0, stream>>>(htmp, a_src2, a_dst2, esrc, edst);
  k_emax<<<32, 256, 0, stream>>>(edst, mask, Mmax);
  k_attn_mfma<2><<<512, 256, 0, stream>>>(hT, esrc, edst, Mmax, mask, nullptr, ln2_g, ln2_b, h2);

  // ---- heads ----
  k_gemm<<<512, 256, 0, stream>>>(h2, Wa, ba, out, 64);
  k_myemb<<<1, 256, 0, stream>>>(h2, idx, Wm, bm, out);
}

// Round 15
// 235.815 us; speedup vs baseline: 2.3352x; 1.0309x over previous
//
#include <hip/hip_runtime.h>
#include <hip/hip_bf16.h>

// Sizes: B=8, N=1024, hidden=256, H=4 heads, D=64, entity=31
typedef _Float16 f16x8 __attribute__((ext_vector_type(8)));
typedef float f32x4 __attribute__((ext_vector_type(4)));

// ---------------------------------------------------------------------------
__global__ __launch_bounds__(256) void k_proj(
    const float* __restrict__ agents, const int* __restrict__ my_id,
    const float* __restrict__ Wp, const float* __restrict__ bp,
    float* __restrict__ proj, float* __restrict__ mask, int* __restrict__ idx)
{
  int blk = blockIdx.x;
  int b = blk >> 10, n = blk & 1023;
  __shared__ float arow[32];
  int t = threadIdx.x;
  if (t < 31) arow[t] = agents[((size_t)(b * 1024 + n)) * 31 + t];
  __syncthreads();
  float id = arow[0];
  int npc = (int)arow[1];
  float acc = bp[t] + id * Wp[t] + Wp[(1 + npc) * 256 + t];
#pragma unroll
  for (int c = 2; c < 31; ++c) acc += arow[c] * Wp[(4 + c) * 256 + t];
  proj[((size_t)(b * 1024 + n)) * 256 + t] = acc;
  if (t == 0) {
    mask[b * 1024 + n] = (id != 0.f) ? 1.f : 0.f;
    if (id == (float)my_id[b]) atomicMin(&idx[b], n);
  }
}

// ---------------------------------------------------------------------------
// k_wt: W fp32 [K][256] -> Wt fp32 [256][K]; grid = (K/32)*8, 256 thr
__global__ __launch_bounds__(256) void k_wt(
    const float* __restrict__ W, float* __restrict__ Wt, int K)
{
  __shared__ float tl[32][33];
  int bk = blockIdx.x >> 3, bj = blockIdx.x & 7;
  int tc = threadIdx.x & 31, tr = threadIdx.x >> 5;  // tr 0..7
#pragma unroll
  for (int r = 0; r < 4; ++r) {
    int row = tr * 4 + r;
    tl[row][tc] = W[(size_t)(bk * 32 + row) * 256 + bj * 32 + tc];
  }
  __syncthreads();
#pragma unroll
  for (int r = 0; r < 4; ++r) {
    int row = tr * 4 + r;
    Wt[(size_t)(bj * 32 + row) * K + bk * 32 + tc] = tl[tc][row];
  }
}

// ---------------------------------------------------------------------------
// k_gemm_mfma: C[8192x256] = A[8192xK] * B[Kx256] (+bias) via split-fp16 MFMA.
// B passed pre-transposed fp32 [256][K] (k_wt). Each fp32 operand is split
// x = hi(fp16) + lo(fp16 residual); C += AhBh + AhBl + AlBh  (error ~2^-22,
// fp32-equivalent -- REQUIRED: proj values O(1e3) would corrupt softmax
// logits under naive fp16). Tile 64x64, 4 waves, wave = 16 rows x 64 cols.
template <int K>
__global__ __launch_bounds__(256) void k_gemm_mfma(
    const float* __restrict__ A, const float* __restrict__ BtF,
    const float* __restrict__ bias, float* __restrict__ C)
{
  __shared__ __align__(16) _Float16 AsH[64 * 40], AsL[64 * 40];
  __shared__ __align__(16) _Float16 BsH[64 * 40], BsL[64 * 40];
  int t = threadIdx.x;
  int w = t >> 6, l = t & 63;
  int bi = blockIdx.x >> 2, bj = blockIdx.x & 3;
  int i0 = bi << 6, j0 = bj << 6;
  int srow = t >> 2, skq = (t & 3) << 3;  // staging: row/col 0..63, k-off 0/8/16/24

  f32x4 C0 = {0.f, 0.f, 0.f, 0.f}, C1 = C0, C2 = C0, C3 = C0;

  for (int k0 = 0; k0 < K; k0 += 32) {
    // ---- stage A (fp32 -> hi/lo fp16) ----
    {
      const float* ap = A + (size_t)(i0 + srow) * K + k0 + skq;
      float4 a0 = *(const float4*)ap, a1 = *(const float4*)(ap + 4);
      float av[8] = {a0.x, a0.y, a0.z, a0.w, a1.x, a1.y, a1.z, a1.w};
      _Float16 hi[8], lo[8];
#pragma unroll
      for (int q = 0; q < 8; ++q) {
        hi[q] = (_Float16)av[q];
        lo[q] = (_Float16)(av[q] - (float)hi[q]);
      }
      *(uint4*)&AsH[srow * 40 + skq] = *(const uint4*)hi;
      *(uint4*)&AsL[srow * 40 + skq] = *(const uint4*)lo;
    }
    // ---- stage B from transposed weights (coalesced) ----
    {
      const float* bp = BtF + (size_t)(j0 + srow) * K + k0 + skq;
      float4 b0 = *(const float4*)bp, b1 = *(const float4*)(bp + 4);
      float bv[8] = {b0.x, b0.y, b0.z, b0.w, b1.x, b1.y, b1.z, b1.w};
      _Float16 hi[8], lo[8];
#pragma unroll
      for (int q = 0; q < 8; ++q) {
        hi[q] = (_Float16)bv[q];
        lo[q] = (_Float16)(bv[q] - (float)hi[q]);
      }
      *(uint4*)&BsH[srow * 40 + skq] = *(const uint4*)hi;
      *(uint4*)&BsL[srow * 40 + skq] = *(const uint4*)lo;
    }
    __syncthreads();
    // ---- fragments + MFMA: A row = l&15, k = (l>>4)*8+q; B col = l&15 ----
    int fr = l & 15;
    int fk = (l >> 4) << 3;
    f16x8 ah = *(const f16x8*)&AsH[(w * 16 + fr) * 40 + fk];
    f16x8 al = *(const f16x8*)&AsL[(w * 16 + fr) * 40 + fk];
    {
      f16x8 bh = *(const f16x8*)&BsH[(0 * 16 + fr) * 40 + fk];
      f16x8 bl = *(const f16x8*)&BsL[(0 * 16 + fr) * 40 + fk];
      C0 = __builtin_amdgcn_mfma_f32_16x16x32_f16(ah, bh, C0, 0, 0, 0);
      C0 = __builtin_amdgcn_mfma_f32_16x16x32_f16(ah, bl, C0, 0, 0, 0);
      C0 = __builtin_amdgcn_mfma_f32_16x16x32_f16(al, bh, C0, 0, 0, 0);
    }
    {
      f16x8 bh = *(const f16x8*)&BsH[(1 * 16 + fr) * 40 + fk];
      f16x8 bl = *(const f16x8*)&BsL[(1 * 16 + fr) * 40 + fk];
      C1 = __builtin_amdgcn_mfma_f32_16x16x32_f16(ah, bh, C1, 0, 0, 0);
      C1 = __builtin_amdgcn_mfma_f32_16x16x32_f16(ah, bl, C1, 0, 0, 0);
      C1 = __builtin_amdgcn_mfma_f32_16x16x32_f16(al, bh, C1, 0, 0, 0);
    }
    {
      f16x8 bh = *(const f16x8*)&BsH[(2 * 16 + fr) * 40 + fk];
      f16x8 bl = *(const f16x8*)&BsL[(2 * 16 + fr) * 40 + fk];
      C2 = __builtin_amdgcn_mfma_f32_16x16x32_f16(ah, bh, C2, 0, 0, 0);
      C2 = __builtin_amdgcn_mfma_f32_16x16x32_f16(ah, bl, C2, 0, 0, 0);
      C2 = __builtin_amdgcn_mfma_f32_16x16x32_f16(al, bh, C2, 0, 0, 0);
    }
    {
      f16x8 bh = *(const f16x8*)&BsH[(3 * 16 + fr) * 40 + fk];
      f16x8 bl = *(const f16x8*)&BsL[(3 * 16 + fr) * 40 + fk];
      C3 = __builtin_amdgcn_mfma_f32_16x16x32_f16(ah, bh, C3, 0, 0, 0);
      C3 = __builtin_amdgcn_mfma_f32_16x16x32_f16(ah, bl, C3, 0, 0, 0);
      C3 = __builtin_amdgcn_mfma_f32_16x16x32_f16(al, bh, C3, 0, 0, 0);
    }
    __syncthreads();
  }

  // epilogue: C/D layout col = lane&15, row = (lane>>4)*4 + r  (m89)
  int rbase = i0 + w * 16 + ((l >> 4) << 2);
  int cb = j0 + (l & 15);
  float b0 = bias ? bias[cb] : 0.f;
  float b1 = bias ? bias[cb + 16] : 0.f;
  float b2 = bias ? bias[cb + 32] : 0.f;
  float b3 = bias ? bias[cb + 48] : 0.f;
#pragma unroll
  for (int r = 0; r < 4; ++r) {
    size_t ro = (size_t)(rbase + r) * 256;
    C[ro + cb]      = C0[r] + b0;
    C[ro + cb + 16] = C1[r] + b1;
    C[ro + cb + 32] = C2[r] + b2;
    C[ro + cb + 48] = C3[r] + b3;
  }
}

// ---------------------------------------------------------------------------
__global__ __launch_bounds__(256) void k_edges(
    const float* __restrict__ h, const float* __restrict__ a_src,
    const float* __restrict__ a_dst, float* __restrict__ esrc, float* __restrict__ edst)
{
  __shared__ float as_[256], ad_[256];
  int t = threadIdx.x;
  as_[t] = a_src[t];
  ad_[t] = a_dst[t];
  __syncthreads();
  int w = t >> 6, l = t & 63;
  int row = blockIdx.x * 4 + w;
  const float* x = h + (size_t)row * 256;
  float ps[4], pd[4];
#pragma unroll
  for (int hh = 0; hh < 4; ++hh) {
    float v = x[hh * 64 + l];
    ps[hh] = v * as_[hh * 64 + l];
    pd[hh] = v * ad_[hh * 64 + l];
  }
#pragma unroll
  for (int hh = 0; hh < 4; ++hh) {
    for (int o = 32; o; o >>= 1) {
      ps[hh] += __shfl_down(ps[hh], o);
      pd[hh] += __shfl_down(pd[hh], o);
    }
  }
  if (l == 0) {
    int b = row >> 10, n = row & 1023;
#pragma unroll
    for (int hh = 0; hh < 4; ++hh) {
      esrc[((b * 4 + hh) << 10) + n] = ps[hh];
      edst[((b * 4 + hh) << 10) + n] = pd[hh];
    }
  }
}

// ---------------------------------------------------------------------------
__global__ __launch_bounds__(256) void k_emax(
    const float* __restrict__ edst, const float* __restrict__ mask, float* __restrict__ Mmax)
{
  int bh = blockIdx.x;
  int b = bh >> 2;
  int t = threadIdx.x;
  float v = -1e30f;
  for (int j = t; j < 1024; j += 256)
    if (mask[(b << 10) + j] != 0.f) v = fmaxf(v, edst[(bh << 10) + j]);
  for (int o = 32; o; o >>= 1) v = fmaxf(v, __shfl_down(v, o));
  __shared__ float red[4];
  if ((t & 63) == 0) red[t >> 6] = v;
  __syncthreads();
  if (t == 0) Mmax[bh] = fmaxf(fmaxf(red[0], red[1]), fmaxf(red[2], red[3]));
}

// ---------------------------------------------------------------------------
// k_prep: h fp32 [B][N][256] -> hT fp16 chunk-tiled [B][H][32 c][64 d][32 j]
__global__ __launch_bounds__(256) void k_prep(
    const float* __restrict__ h, _Float16* __restrict__ hT)
{
  int blk = blockIdx.x;
  int c = blk & 31, hh = (blk >> 5) & 3, b = blk >> 7;
  int t = threadIdx.x;
  __shared__ _Float16 tile[32][72];
  {
    int jr = t >> 3, dg = t & 7;
    const float* src = h + ((size_t)(b * 1024 + c * 32 + jr)) * 256 + hh * 64 + dg * 8;
    float4 a = *(const float4*)src;
    float4 b4 = *(const float4*)(src + 4);
    _Float16* tp = &tile[jr][dg * 8];
    tp[0] = (_Float16)a.x;  tp[1] = (_Float16)a.y;  tp[2] = (_Float16)a.z;  tp[3] = (_Float16)a.w;
    tp[4] = (_Float16)b4.x; tp[5] = (_Float16)b4.y; tp[6] = (_Float16)b4.z; tp[7] = (_Float16)b4.w;
  }
  __syncthreads();
  {
    int d = t >> 2, q = t & 3;
    _Float16 o[8];
#pragma unroll
    for (int s = 0; s < 8; ++s) o[s] = tile[q * 8 + s][d];
    _Float16* dst = hT + ((size_t)((b * 4 + hh) * 32 + c)) * 2048 + d * 32 + q * 8;
    *(uint4*)dst = *(const uint4*)o;
  }
}

// ---------------------------------------------------------------------------
// k_attn_mfma: P·h via mfma_f32_16x16x32_f16 (verified R14, absmax 0.0078).
template <int LAYER>
__global__ __launch_bounds__(256) void k_attn_mfma(
    const _Float16* __restrict__ hT, const float* __restrict__ esrc,
    const float* __restrict__ edst, const float* __restrict__ Mmax,
    const float* __restrict__ mask, const float* __restrict__ resid,
    const float* __restrict__ g, const float* __restrict__ be,
    float* __restrict__ out)
{
  __shared__ __align__(16) char smem[40960];
  __shared__ float esrcL[16][4], mL[16][4];
  __shared__ float maskL[16], MhL[4];
  __shared__ float sInvS[4][16];
  __shared__ float statM[16], statR[16];

  int t = threadIdx.x;
  int hID = t >> 6, l = t & 63;
  int b = blockIdx.x & 7;
  int it = blockIdx.x >> 3;
  int i0 = it << 4;

  if (t < 16) maskL[t] = mask[(b << 10) + i0 + t];
  if (t < 4) MhL[t] = Mmax[(b << 2) + t];
  if (t < 64) {
    int ii = t >> 2, hh = t & 3;
    esrcL[ii][hh] = esrc[(((b << 2) + hh) << 10) + i0 + ii];
  }
  __syncthreads();
  if (t < 64) {
    int ii = t >> 2, hh = t & 3;
    float m = 0.f;
    if (maskL[ii] != 0.f) {
      float v = esrcL[ii][hh] + MhL[hh];
      m = v > 0.f ? v : 0.2f * v;
    }
    mL[ii][hh] = m;
  }
  __syncthreads();

  int iloc = l & 15;
  float esr = esrcL[iloc][hID];
  float mr = mL[iloc][hID];
  float mskI = maskL[iloc];
  int jg = (l >> 4) << 3;

  const float* ej_base = edst + (((b << 2) + hID) << 10);
  const float* mk_base = mask + (b << 10);
  const char* gT = (const char*)hT + ((size_t)((b * 4 + hID) * 32)) * 4096;
  char* hb = smem + hID * 10240;

  f32x4 C0 = {0.f,0.f,0.f,0.f}, C1 = C0, C2 = C0, C3 = C0;
  float sp = 0.f;

  {
    const uint4* gs = (const uint4*)(gT + l * 64);
    uint4 s0 = gs[0], s1 = gs[1], s2 = gs[2], s3 = gs[3];
    uint4* wp = (uint4*)(hb + l * 80);
    wp[0] = s0; wp[1] = s1; wp[2] = s2; wp[3] = s3;
  }
  int cur = 0;

  for (int c = 0; c < 32; ++c) {
    uint4 n0, n1, n2, n3;
    if (c < 31) {
      const uint4* gs = (const uint4*)(gT + (size_t)(c + 1) * 4096 + l * 64);
      n0 = gs[0]; n1 = gs[1]; n2 = gs[2]; n3 = gs[3];
    }
    int j0 = c << 5;
    float4 e0 = *(const float4*)(ej_base + j0 + jg);
    float4 e1 = *(const float4*)(ej_base + j0 + jg + 4);
    float4 m0 = *(const float4*)(mk_base + j0 + jg);
    float4 m1 = *(const float4*)(mk_base + j0 + jg + 4);
    float w[8];
    float ev[8] = {e0.x, e0.y, e0.z, e0.w, e1.x, e1.y, e1.z, e1.w};
    float mv[8] = {m0.x, m0.y, m0.z, m0.w, m1.x, m1.y, m1.z, m1.w};
    if (mskI != 0.f) {
#pragma unroll
      for (int q = 0; q < 8; ++q) {
        float v = esr + ev[q];
        v = v > 0.f ? v : 0.2f * v;
        w[q] = (mv[q] != 0.f) ? __expf(v - mr) : 0.f;
      }
    } else {
#pragma unroll
      for (int q = 0; q < 8; ++q) w[q] = 1.f;
    }
    f16x8 af;
#pragma unroll
    for (int q = 0; q < 8; ++q) { sp += w[q]; af[q] = (_Float16)w[q]; }
    const char* rp = hb + cur * 5120 + (l & 15) * 80 + (l >> 4) * 16;
    f16x8 b0 = *(const f16x8*)(rp);
    f16x8 b1 = *(const f16x8*)(rp + 1280);
    f16x8 b2 = *(const f16x8*)(rp + 2560);
    f16x8 b3 = *(const f16x8*)(rp + 3840);
    C0 = __builtin_amdgcn_mfma_f32_16x16x32_f16(af, b0, C0, 0, 0, 0);
    C1 = __builtin_amdgcn_mfma_f32_16x16x32_f16(af, b1, C1, 0, 0, 0);
    C2 = __builtin_amdgcn_mfma_f32_16x16x32_f16(af, b2, C2, 0, 0, 0);
    C3 = __builtin_amdgcn_mfma_f32_16x16x32_f16(af, b3, C3, 0, 0, 0);
    if (c < 31) {
      uint4* wp = (uint4*)(hb + (cur ^ 1) * 5120 + l * 80);
      wp[0] = n0; wp[1] = n1; wp[2] = n2; wp[3] = n3;
      cur ^= 1;
    }
  }

  sp += __shfl_xor(sp, 16);
  sp += __shfl_xor(sp, 32);
  if (l < 16) sInvS[hID][l] = 1.f / sp;
  __syncthreads();

  float (*y)[256] = (float (*)[256])smem;
  {
    int rbase = (l >> 4) << 2;
    int col = (hID << 6) + (l & 15);
#pragma unroll
    for (int r = 0; r < 4; ++r) {
      float sv = sInvS[hID][rbase + r];
      y[rbase + r][col +  0] = C0[r] * sv;
      y[rbase + r][col + 16] = C1[r] * sv;
      y[rbase + r][col + 32] = C2[r] * sv;
      y[rbase + r][col + 48] = C3[r] * sv;
    }
  }
  __syncthreads();

  if (LAYER == 1) {
#pragma unroll
    for (int i = 0; i < 16; ++i)
      y[i][t] += resid[((size_t)(b * 1024 + i0 + i)) * 256 + t];
    __syncthreads();
#pragma unroll
    for (int rr = 0; rr < 4; ++rr) {
      int i = (hID << 2) + rr;
      float v0 = y[i][l], v1 = y[i][64 + l], v2 = y[i][128 + l], v3 = y[i][192 + l];
      float s = v0 + v1 + v2 + v3;
      float q = v0 * v0 + v1 * v1 + v2 * v2 + v3 * v3;
      for (int o = 32; o; o >>= 1) { s += __shfl_xor(s, o); q += __shfl_xor(q, o); }
      if (l == 0) {
        float mean = s * (1.f / 256.f);
        float var = q * (1.f / 256.f) - mean * mean;
        statM[i] = mean;
        statR[i] = rsqrtf(var + 1e-5f);
      }
    }
    __syncthreads();
#pragma unroll
    for (int i = 0; i < 16; ++i) {
      float yv = y[i][t];
      float o_ = (yv - statM[i]) * statR[i] * g[t] + be[t];
      out[((size_t)(b * 1024 + i0 + i)) * 256 + t] = fmaxf(o_, 0.f);
    }
  } else {
#pragma unroll
    for (int rr = 0; rr < 4; ++rr) {
      int i = (hID << 2) + rr;
      float v = 0.25f * (y[i][l] + y[i][64 + l] + y[i][128 + l] + y[i][192 + l]);
      float s = v, q = v * v;
      for (int o = 32; o; o >>= 1) { s += __shfl_xor(s, o); q += __shfl_xor(q, o); }
      float mean = s * (1.f / 64.f);
      float var = q * (1.f / 64.f) - mean * mean;
      float rstd = rsqrtf(var + 1e-5f);
      float o_ = (v - mean) * rstd * g[l] + be[l];
      out[((size_t)(b * 1024 + i0 + i)) * 64 + l] = fmaxf(o_, 0.f);
    }
  }
}

// ---------------------------------------------------------------------------
__global__ __launch_bounds__(256) void k_myemb(
    const float* __restrict__ h2, const int* __restrict__ idx,
    const float* __restrict__ Wm, const float* __restrict__ bm, float* __restrict__ out)
{
  __shared__ float row[64];
  int t = threadIdx.x;
  for (int b = 0; b < 8; ++b) {
    int n = idx[b];
    if (t < 64) row[t] = h2[((size_t)(b * 1024 + n)) * 64 + t];
    __syncthreads();
    float acc = bm[t];
#pragma unroll
    for (int d = 0; d < 64; ++d) acc += row[d] * Wm[d * 256 + t];
    out[2097152 + b * 256 + t] = fmaxf(acc, 0.f);
    __syncthreads();
  }
}

// ---------------------------------------------------------------------------
extern "C" void kernel_launch(void* const* d_in, const int* in_sizes, int n_in,
                              void* d_out, int out_size, void* d_ws, size_t ws_size,
                              hipStream_t stream) {
  const float* agents = (const float*)d_in[0];
  const int* my_id = (const int*)d_in[1];
  const float* Wp = (const float*)d_in[2];
  const float* bp = (const float*)d_in[3];
  const float* W1 = (const float*)d_in[4];
  const float* a_src1 = (const float*)d_in[5];
  const float* a_dst1 = (const float*)d_in[6];
  const float* ln1_g = (const float*)d_in[7];
  const float* ln1_b = (const float*)d_in[8];
  const float* W2 = (const float*)d_in[9];
  const float* a_src2 = (const float*)d_in[10];
  const float* a_dst2 = (const float*)d_in[11];
  const float* ln2_g = (const float*)d_in[12];
  const float* ln2_b = (const float*)d_in[13];
  const float* Wa = (const float*)d_in[14];
  const float* ba = (const float*)d_in[15];
  const float* Wm = (const float*)d_in[16];
  const float* bm = (const float*)d_in[17];
  float* out = (float*)d_out;

  float* W = (float*)d_ws;
  float* mask = W;                    // 8192
  float* Mmax = W + 8192;             // 32
  int* idx = (int*)(W + 8224);        // 8 ints
  float* esrc = W + 16384;            // 32768  [B][H][N]
  float* edst = W + 49152;            // 32768
  float* proj = W + 81920;            // 2097152
  float* htmp = W + 2179072;          // 2097152
  float* h1 = W + 4276224;            // 2097152
  float* h2 = W + 6373376;            // 524288
  _Float16* hT = (_Float16*)(W + 6897664);  // 4 MB (2M halfs)
  float* Wt1 = W + 7946240;           // 65536  [256][256]
  float* Wt2 = W + 8011776;           // 65536
  float* Wta = W + 8077312;           // 16384  [256][64]

  hipMemsetAsync(idx, 0x7F, 8 * sizeof(int), stream);
  k_proj<<<8192, 256, 0, stream>>>(agents, my_id, Wp, bp, proj, mask, idx);
  k_wt<<<64, 256, 0, stream>>>(W1, Wt1, 256);
  k_wt<<<64, 256, 0, stream>>>(W2, Wt2, 256);
  k_wt<<<16, 256, 0, stream>>>(Wa, Wta, 64);

  // ---- layer 1 ----
  k_gemm_mfma<256><<<512, 256, 0, stream>>>(proj, Wt1, nullptr, htmp);
  k_prep<<<1024, 256, 0, stream>>>(htmp, hT);
  k_edges<<<2048, 256, 0, stream>>>(htmp, a_src1, a_dst1, esrc, edst);
  k_emax<<<32, 256, 0, stream>>>(edst, mask, Mmax);
  k_attn_mfma<1><<<512, 256, 0, stream>>>(hT, esrc, edst, Mmax, mask, proj, ln1_g, ln1_b, h1);

  // ---- layer 2 ----
  k_gemm_mfma<256><<<512, 256, 0, stream>>>(h1, Wt2, nullptr, htmp);
  k_prep<<<1024, 256, 0, stream>>>(htmp, hT);
  k_edges<<<2048, 256, 0, stream>>>(htmp, a_src2, a_dst2, esrc, edst);
  k_emax<<<32, 256, 0, stream>>>(edst, mask, Mmax);
  k_attn_mfma<2><<<512, 256, 0, stream>>>(hT, esrc, edst, Mmax, mask, nullptr, ln2_g, ln2_b, h2);

  // ---- heads ----
  k_gemm_mfma<64><<<512, 256, 0, stream>>>(h2, Wta, ba, out);
  k_myemb<<<1, 256, 0, stream>>>(h2, idx, Wm, bm, out);
}